// Round 7
// baseline (753.990 us; speedup 1.0000x reference)
//
#include <hip/hip_runtime.h>

#define NEG_SLOPE 0.2f
typedef unsigned int u32;

// ------------------------------------------------------------ build bitmasks
__global__ __launch_bounds__(256) void k_build(const int* __restrict__ ei,
                                               u32* __restrict__ Mb,
                                               u32* __restrict__ Rb, int E)
{
    int e = blockIdx.x * 256 + threadIdx.x;
    if (e >= E) return;
    int s = ei[e], d = ei[E + e];
    int g = s >> 7, ls = s & 127, ld = d & 127;
    atomicOr(&Mb[(g * 128 + ld) * 4 + (ls >> 5)], 1u << (ls & 31));  // col mask (in-edges)
    atomicOr(&Rb[(g * 128 + ls) * 4 + (ld >> 5)], 1u << (ld & 31));  // row mask (out-edges)
}

// ------------------------------------- precompute v = lin_w^T a_q, c0 = lin_b·a_q
__global__ __launch_bounds__(128) void k_prep(
    const float* __restrict__ lin_w, const float* __restrict__ lin_b,
    const float* __restrict__ att_w,
    float* __restrict__ v_out, float* __restrict__ c0_out)
{
    const int p = blockIdx.x;
    const float* lw = lin_w + p * 16384;
    const float* lb = lin_b + p * 128;
    const float* aw = att_w + p * 256;
    const int c = threadIdx.x;
    float s = 0.f;
    for (int c2 = 0; c2 < 128; ++c2) s += aw[c2] * lw[c2 * 128 + c];
    v_out[p * 128 + c] = s;
    if (c < 64) {
        float s0 = aw[c] * lb[c] + aw[c + 64] * lb[c + 64];
        for (int off = 32; off; off >>= 1) s0 += __shfl_xor(s0, off);
        if (c == 0) c0_out[p] = s0;
    }
}

// --------------------------------------------- agg = (A^T h)/deg, binary A
__global__ __launch_bounds__(512) void k_agg_mask(
    const float* __restrict__ h, const u32* __restrict__ Mb,
    float* __restrict__ agg, int n, int Cin)
{
    const int g = blockIdx.x;
    const int q4 = Cin >> 2;
    int idx = blockIdx.y * 512 + threadIdx.x;
    if (idx >= n * q4) return;
    int j = idx / q4, c4 = (idx - j * q4) << 2;
    const u32* m = Mb + (g * 128 + j) * 4;
    u32 m0 = m[0], m1 = m[1], m2 = m[2], m3 = m[3];
    float dv = fmaxf((float)(__popc(m0) + __popc(m1) + __popc(m2) + __popc(m3)), 1.0f);
    const float* hg = h + (size_t)g * n * Cin + c4;
    float sx = 0.f, sy = 0.f, sz = 0.f, sw = 0.f;
    u32 wds[4] = { m0, m1, m2, m3 };
    #pragma unroll
    for (int ww = 0; ww < 4; ++ww) {
        u32 u = wds[ww];
        while (u) {
            int i = (ww << 5) + __ffs(u) - 1; u &= u - 1u;
            float4 hv = *(const float4*)(hg + (size_t)i * Cin);
            sx += hv.x; sy += hv.y; sz += hv.z; sw += hv.w;
        }
    }
    float4 o; o.x = sx / dv; o.y = sy / dv; o.z = sz / dv; o.w = sw / dv;
    *(float4*)(agg + ((size_t)g * n + j) * Cin + c4) = o;
}

// --------------------------------------------- agg = (A^T h)/deg, dense A via A^T
__global__ __launch_bounds__(512) void k_agg_dense(
    const float* __restrict__ h, const float* __restrict__ AT,
    const u32* __restrict__ Mb, float* __restrict__ agg, int n)
{
    const int C = 128;
    const int g = blockIdx.x;
    int idx = blockIdx.y * 512 + threadIdx.x;
    if (idx >= n * 32) return;
    int j = idx >> 5, c4 = (idx & 31) << 2;
    const u32* m = Mb + (g * 128 + j) * 4;
    float dv = fmaxf((float)(__popc(m[0]) + __popc(m[1]) + __popc(m[2]) + __popc(m[3])), 1.0f);
    const float* Aj = AT + ((size_t)g * n + j) * n;     // AT[j][i] = A[i][j]
    const float* hg = h + (size_t)g * n * C + c4;
    float sx = 0.f, sy = 0.f, sz = 0.f, sw = 0.f;
    for (int i = 0; i < n; ++i) {
        float a = Aj[i];
        float4 hv = *(const float4*)(hg + (size_t)i * C);
        sx += a * hv.x; sy += a * hv.y; sz += a * hv.z; sw += a * hv.w;
    }
    float4 o; o.x = sx / dv; o.y = sy / dv; o.z = sz / dv; o.w = sw / dv;
    *(float4*)(agg + ((size_t)g * n + j) * C + c4) = o;
}

// ------- out = relu(agg@wrel^T + brel + h@wroot^T), fused gpool partial sums
// group of L=Cin/2 lanes owns one row; X in registers; no inner barriers.
template<int CIN>
__global__ __launch_bounds__(512) void k_out(
    const float* __restrict__ h, const float* __restrict__ agg,
    const float* __restrict__ wrel, const float* __restrict__ brel,
    const float* __restrict__ wroot,
    float* __restrict__ h_out, float* __restrict__ xs,
    int n)
{
    constexpr int L = CIN >> 1;        // lanes per row-group (32 or 64)
    constexpr int G = 512 / L;         // rows per block (16 or 8)
    constexpr int HALF = L >> 1;       // float4 slots per operand
    const int g = blockIdx.x;
    const int gg = threadIdx.x / L;
    const int l  = threadIdx.x % L;
    const int jg = blockIdx.y * G + gg;
    __shared__ float tile[G * 128];

    if (jg < n) {
        const float* xsrc = (l < HALF)
            ? (agg + ((size_t)g * n + jg) * CIN + (l << 2))
            : (h   + ((size_t)g * n + jg) * CIN + ((l - HALF) << 2));
        const float4 xv = *(const float4*)xsrc;
        const float* wbase = (l < HALF) ? (wrel + (l << 2))
                                        : (wroot + ((l - HALF) << 2));
        for (int c2 = 0; c2 < 128; ++c2) {
            float4 wv = *(const float4*)(wbase + (size_t)c2 * CIN);
            float acc = xv.x * wv.x + xv.y * wv.y + xv.z * wv.z + xv.w * wv.w;
            #pragma unroll
            for (int off = L >> 1; off; off >>= 1)
                acc += __shfl_xor(acc, off, L);
            if (l == 0) tile[gg * 128 + c2] = fmaxf(acc + brel[c2], 0.0f);
        }
    } else {
        for (int c2 = l; c2 < 128; c2 += L) tile[gg * 128 + c2] = 0.0f;
    }
    __syncthreads();

    const int tid = threadIdx.x;
    // coalesced h_out writes
    for (int idx = tid; idx < G * 32; idx += 512) {
        int r = idx >> 5, c4 = (idx & 31) << 2;
        int j2 = blockIdx.y * G + r;
        if (j2 < n)
            *(float4*)(h_out + ((size_t)g * n + j2) * 128 + c4) =
                *(const float4*)(tile + r * 128 + c4);
    }
    // gpool partials: one atomic per column per block
    if (tid < 128) {
        float s = 0.f;
        #pragma unroll
        for (int r = 0; r < G; ++r) s += tile[r * 128 + tid];
        atomicAdd(&xs[g * 128 + tid], s / (float)n);
    }
}

// ------------- pool stage 1a: qa[j] = maskedColMax(h)·v + c0 ; xa[i] = h[i]·a_x
__global__ __launch_bounds__(512) void k_attn(
    const float* __restrict__ h, const u32* __restrict__ Mb_g,
    const float* __restrict__ v_g, const float* __restrict__ c0_g,
    const float* __restrict__ att_w,
    float* __restrict__ qa_g, float* __restrict__ xa_g, int n)
{
    const int g = blockIdx.x;
    const int tid = threadIdx.x;
    const int hw = tid >> 5, ln = tid & 31;
    const float* hg = h + (size_t)g * n * 128;
    const int j = blockIdx.y * 16 + hw;
    if (j < n) {
        u32 m[4];
        m[0] = Mb_g[(g * 128 + j) * 4 + 0]; m[1] = Mb_g[(g * 128 + j) * 4 + 1];
        m[2] = Mb_g[(g * 128 + j) * 4 + 2]; m[3] = Mb_g[(g * 128 + j) * 4 + 3];
        m[j >> 5] |= 1u << (j & 31);                  // diagonal
        float4 mx = make_float4(-1e30f, -1e30f, -1e30f, -1e30f);
        #pragma unroll
        for (int ww = 0; ww < 4; ++ww) {
            u32 u = m[ww];
            while (u) {
                int i = (ww << 5) + __ffs(u) - 1; u &= u - 1u;
                float4 hv = *(const float4*)(hg + (size_t)i * 128 + ln * 4);
                mx.x = fmaxf(mx.x, hv.x); mx.y = fmaxf(mx.y, hv.y);
                mx.z = fmaxf(mx.z, hv.z); mx.w = fmaxf(mx.w, hv.w);
            }
        }
        float4 vv = *(const float4*)(v_g + ln * 4);
        float acc = mx.x * vv.x + mx.y * vv.y + mx.z * vv.z + mx.w * vv.w;
        #pragma unroll
        for (int off = 16; off; off >>= 1) acc += __shfl_xor(acc, off, 32);
        if (ln == 0) qa_g[g * 128 + j] = acc + c0_g[0];
    }
    const int i = blockIdx.y * 16 + hw;
    if (i < n) {
        float4 hv = *(const float4*)(hg + (size_t)i * 128 + ln * 4);
        float4 aw = *(const float4*)(att_w + 128 + ln * 4);
        float s = hv.x * aw.x + hv.y * aw.y + hv.z * aw.z + hv.w * aw.w;
        #pragma unroll
        for (int off = 16; off; off >>= 1) s += __shfl_xor(s, off, 32);
        if (ln == 0) xa_g[g * 128 + i] = s;
    }
}

// ------------- pool stage 1b: masked column softmax -> S_cm (wave per column)
__global__ __launch_bounds__(512) void k_soft(
    const u32* __restrict__ Mb_g, const float* __restrict__ qa_g,
    const float* __restrict__ xa_g, const float* __restrict__ att_bp,
    float* __restrict__ S_cm, int n)
{
    const int g = blockIdx.x;
    const int tid = threadIdx.x, lane = tid & 63, wid = tid >> 6;
    const int j = blockIdx.y * 8 + wid;
    if (j >= n) return;
    const float att_b = att_bp[0];
    u32 m[4];
    m[0] = Mb_g[(g * 128 + j) * 4 + 0]; m[1] = Mb_g[(g * 128 + j) * 4 + 1];
    m[2] = Mb_g[(g * 128 + j) * 4 + 2]; m[3] = Mb_g[(g * 128 + j) * 4 + 3];
    m[j >> 5] |= 1u << (j & 31);                      // diagonal
    const float qaj = qa_g[g * 128 + j];
    const int i0 = lane, i1 = lane + 64;
    const bool b0 = (i0 < n) && ((m[i0 >> 5] >> (i0 & 31)) & 1u);
    const bool b1 = (i1 < n) && ((m[i1 >> 5] >> (i1 & 31)) & 1u);
    float l0 = -1e30f, l1 = -1e30f;
    if (b0) { float t = xa_g[g * 128 + i0] + qaj + att_b; l0 = (t >= 0.f) ? t : NEG_SLOPE * t; }
    if (b1) { float t = xa_g[g * 128 + i1] + qaj + att_b; l1 = (t >= 0.f) ? t : NEG_SLOPE * t; }
    float mm = fmaxf(l0, l1);
    for (int off = 32; off; off >>= 1) mm = fmaxf(mm, __shfl_xor(mm, off));
    float e0 = b0 ? expf(l0 - mm) : 0.f;
    float e1 = b1 ? expf(l1 - mm) : 0.f;
    float s = e0 + e1;
    for (int off = 32; off; off >>= 1) s += __shfl_xor(s, off);
    float* Sj = S_cm + ((size_t)g * 128 + j) * 128;
    if (i0 < n) Sj[i0] = e0 / s;
    if (i1 < n) Sj[i1] = e1 / s;
}

// ---------------------------------------- pool stage 2: x_new = S_cm @ h
__global__ __launch_bounds__(512) void k_xnew(
    const float* __restrict__ S_cm, const float* __restrict__ h,
    float* __restrict__ xn, int n)
{
    const int g = blockIdx.x;
    int idx = blockIdx.y * 512 + threadIdx.x;
    if (idx >= n * 32) return;
    int j = idx >> 5, c4 = (idx & 31) << 2;
    const float* Sj = S_cm + ((size_t)g * 128 + j) * 128;
    const float* hg = h + (size_t)g * n * 128 + c4;
    float sx = 0.f, sy = 0.f, sz = 0.f, sw = 0.f;
    for (int i = 0; i < n; ++i) {
        float sv = Sj[i];
        float4 hv = *(const float4*)(hg + (size_t)i * 128);
        sx += sv * hv.x; sy += sv * hv.y; sz += sv * hv.z; sw += sv * hv.w;
    }
    float4 o; o.x = sx; o.y = sy; o.z = sz; o.w = sw;
    *(float4*)(xn + ((size_t)g * 128 + j) * 128 + c4) = o;
}

// ------------- pool stage 3: fitness, top-k, h_out, Sselr gathers
__global__ __launch_bounds__(512) void k_fit(
    const float* __restrict__ xn, const u32* __restrict__ Mb_g,
    const float* __restrict__ S_cm,
    const float* __restrict__ le1_w, const float* __restrict__ le1_bp,
    const float* __restrict__ le2_w, const float* __restrict__ le3_w,
    const float* __restrict__ le3_bp,
    float* __restrict__ h_out, float* __restrict__ Sselr, float* __restrict__ SselrT,
    int n, int k, int kpad)
{
    const int g = blockIdx.x;
    const float* xg = xn + (size_t)g * 128 * 128;
    __shared__ float a_s[128], b_s[128], c3_s[128], fit_s[128];
    __shared__ int perm_s[128];
    const int tid = threadIdx.x, lane = tid & 63, wid = tid >> 6;

    for (int j = wid; j < n; j += 8) {
        float x0 = xg[j * 128 + lane], x1 = xg[j * 128 + 64 + lane];
        float s1 = x0 * le1_w[lane] + x1 * le1_w[64 + lane];
        float s2 = x0 * le2_w[lane] + x1 * le2_w[64 + lane];
        float s3 = x0 * le3_w[lane] + x1 * le3_w[64 + lane];
        for (int off = 32; off; off >>= 1) {
            s1 += __shfl_xor(s1, off);
            s2 += __shfl_xor(s2, off);
            s3 += __shfl_xor(s3, off);
        }
        if (lane == 0) { a_s[j] = s1 + le1_bp[0]; b_s[j] = s2; c3_s[j] = s3; }
    }
    __syncthreads();
    for (int j = tid; j < n; j += 512) {
        u32 m[4];
        m[0] = Mb_g[(g * 128 + j) * 4 + 0]; m[1] = Mb_g[(g * 128 + j) * 4 + 1];
        m[2] = Mb_g[(g * 128 + j) * 4 + 2]; m[3] = Mb_g[(g * 128 + j) * 4 + 3];
        m[j >> 5] |= 1u << (j & 31);                  // diagonal
        float dv = (float)(__popc(m[0]) + __popc(m[1]) + __popc(m[2]) + __popc(m[3]));
        float s = 0.f;
        #pragma unroll
        for (int ww = 0; ww < 4; ++ww) {
            u32 u = m[ww];
            while (u) { int i = (ww << 5) + __ffs(u) - 1; u &= u - 1u; s += a_s[i]; }
        }
        float f = s - dv * b_s[j] + c3_s[j] + le3_bp[0];
        fit_s[j] = 1.0f / (1.0f + expf(-f));
    }
    __syncthreads();
    // top-k by rank (ties -> lower index, matches lax.top_k)
    for (int j = tid; j < n; j += 512) {
        float fj = fit_s[j];
        int r = 0;
        for (int j2 = 0; j2 < n; ++j2) {
            float f2 = fit_s[j2];
            if (f2 > fj || (f2 == fj && j2 < j)) ++r;
        }
        if (r < k) perm_s[r] = j;
    }
    __syncthreads();
    // h_out[r] = x_new[perm[r]] * fit[perm[r]]
    for (int idx = tid; idx < k * 32; idx += 512) {
        int r = idx >> 5, c4 = (idx & 31) << 2;
        int p = perm_s[r]; float f = fit_s[p];
        float4 v = *(const float4*)(xg + p * 128 + c4);
        v.x *= f; v.y *= f; v.z *= f; v.w *= f;
        *(float4*)(h_out + ((size_t)g * k + r) * 128 + c4) = v;
    }
    // SselrT[r][i] = S_cm[perm[r]][i]   (row gather, coalesced)
    for (int idx = tid; idx < k * 32; idx += 512) {
        int r = idx >> 5, c4 = (idx & 31) << 2;
        float4 v = *(const float4*)(S_cm + ((size_t)g * 128 + perm_s[r]) * 128 + c4);
        *(float4*)(SselrT + ((size_t)g * 128 + r) * 128 + c4) = v;
    }
    // Sselr[i][cc] = S_cm[perm[cc]][i]  (coalesced reads, scattered 4B writes)
    for (int idx = tid; idx < k * n; idx += 512) {
        int cc = idx / n, i = idx - cc * n;
        Sselr[((size_t)g * 128 + i) * kpad + cc] =
            S_cm[((size_t)g * 128 + perm_s[cc]) * 128 + i];
    }
}

// ---------------------------------------- pool stage 4: T = A_d @ S_sel
__global__ __launch_bounds__(512) void k_T_mask(
    const u32* __restrict__ Rb, const float* __restrict__ Sselr,
    float* __restrict__ T, int n, int k, int kpad)
{
    const int g = blockIdx.x;
    const int ccq = (k + 3) >> 2;
    int idx = blockIdx.y * 512 + threadIdx.x;
    if (idx >= n * ccq) return;
    int i = idx / ccq, c4 = (idx - i * ccq) << 2;
    u32 m[4];
    m[0] = Rb[(g * 128 + i) * 4 + 0]; m[1] = Rb[(g * 128 + i) * 4 + 1];
    m[2] = Rb[(g * 128 + i) * 4 + 2]; m[3] = Rb[(g * 128 + i) * 4 + 3];
    m[i >> 5] |= 1u << (i & 31);                      // diagonal
    float sx = 0.f, sy = 0.f, sz = 0.f, sw = 0.f;
    #pragma unroll
    for (int ww = 0; ww < 4; ++ww) {
        u32 u = m[ww];
        while (u) {
            int j = (ww << 5) + __ffs(u) - 1; u &= u - 1u;
            float4 v = *(const float4*)(Sselr + ((size_t)g * 128 + j) * kpad + c4);
            sx += v.x; sy += v.y; sz += v.z; sw += v.w;
        }
    }
    float4 o; o.x = sx; o.y = sy; o.z = sz; o.w = sw;
    *(float4*)(T + ((size_t)g * 128 + i) * kpad + c4) = o;
}

__global__ __launch_bounds__(512) void k_T_dense(
    const float* __restrict__ A, const float* __restrict__ Sselr,
    float* __restrict__ T, int n, int k, int kpad)
{
    const int g = blockIdx.x;
    const int ccq = (k + 3) >> 2;
    int idx = blockIdx.y * 512 + threadIdx.x;
    if (idx >= n * ccq) return;
    int i = idx / ccq, c4 = (idx - i * ccq) << 2;
    const float* Ai = A + ((size_t)g * n + i) * n;    // unit diag already present
    float sx = 0.f, sy = 0.f, sz = 0.f, sw = 0.f;
    for (int j = 0; j < n; ++j) {
        float a = Ai[j];
        float4 v = *(const float4*)(Sselr + ((size_t)g * 128 + j) * kpad + c4);
        sx += a * v.x; sy += a * v.y; sz += a * v.z; sw += a * v.w;
    }
    float4 o; o.x = sx; o.y = sy; o.z = sz; o.w = sw;
    *(float4*)(T + ((size_t)g * 128 + i) * kpad + c4) = o;
}

// ------------- pool stage 5: A2 = S_sel^T @ T (+diag, +transpose, +mask)
__global__ __launch_bounds__(512) void k_A2(
    const float* __restrict__ SselrT, const float* __restrict__ T,
    float* __restrict__ A_out, float* __restrict__ AT_out,
    u32* __restrict__ Mb_out, int n, int k, int kpad)
{
    const int g = blockIdx.x;
    int idx = blockIdx.y * 512 + threadIdx.x;
    if (idx >= k * k) return;
    int r = idx / k, cc = idx - r * k;
    const float* Sr = SselrT + ((size_t)g * 128 + r) * 128;
    const float* Tg = T + (size_t)g * 128 * kpad;
    float s = 0.f;
    for (int i = 0; i < n; ++i) s += Sr[i] * Tg[i * kpad + cc];
    float val = (r == cc) ? 1.0f : s;
    A_out[((size_t)g * k + r) * k + cc] = val;
    AT_out[((size_t)g * k + cc) * k + r] = val;
    if (val != 0.0f)
        atomicOr(&Mb_out[((size_t)g * 128 + cc) * 4 + (r >> 5)], 1u << (r & 31));
}

// ------------------------------------------------------------- classifier ---
__global__ __launch_bounds__(256) void k_final(
    const float* __restrict__ xs,     // [5][16][128]
    const float* __restrict__ w1, const float* __restrict__ b1,
    const float* __restrict__ w2, const float* __restrict__ b2,
    float* __restrict__ out)
{
    const int g = blockIdx.x;
    __shared__ float j_s[640];
    __shared__ float z1[128];
    const int tid = threadIdx.x, lane = tid & 63, wid = tid >> 6;  // 4 waves

    for (int idx = tid; idx < 640; idx += 256) {
        int t = idx >> 7, c = idx & 127;
        j_s[idx] = xs[t * 2048 + g * 128 + c];
    }
    __syncthreads();
    for (int c2 = wid; c2 < 128; c2 += 4) {
        const float* wrow = w1 + (size_t)c2 * 640;
        float s = 0.f;
        #pragma unroll
        for (int it = 0; it < 10; ++it) {
            int kk = it * 64 + lane;
            s += j_s[kk] * wrow[kk];
        }
        for (int off = 32; off; off >>= 1) s += __shfl_xor(s, off);
        if (lane == 0) z1[c2] = fmaxf(s + b1[c2], 0.0f);
    }
    __syncthreads();
    if (wid == 0) {
        float zv0 = z1[lane], zv1 = z1[lane + 64];
        float za = zv0 * w2[lane] + zv1 * w2[lane + 64];
        float zb = zv0 * w2[128 + lane] + zv1 * w2[192 + lane];
        for (int off = 32; off; off >>= 1) {
            za += __shfl_xor(za, off);
            zb += __shfl_xor(zb, off);
        }
        if (lane == 0) {
            za += b2[0]; zb += b2[1];
            float m = fmaxf(za, zb);
            float lse = m + logf(expf(za - m) + expf(zb - m));
            out[g * 2 + 0] = za - lse;
            out[g * 2 + 1] = zb - lse;
        }
    }
}

// ---------------------------------------------------------------------------
extern "C" void kernel_launch(void* const* d_in, const int* in_sizes, int n_in,
                              void* d_out, int out_size, void* d_ws, size_t ws_size,
                              hipStream_t stream)
{
    (void)n_in; (void)out_size; (void)ws_size;
    const float* x        = (const float*)d_in[0];
    const int*   ei       = (const int*)  d_in[1];
    const float* c0_wrel  = (const float*)d_in[2];
    const float* c0_brel  = (const float*)d_in[3];
    const float* c0_wroot = (const float*)d_in[4];
    const float* cw_rel   = (const float*)d_in[5];
    const float* cb_rel   = (const float*)d_in[6];
    const float* cw_root  = (const float*)d_in[7];
    const float* p_lin_w  = (const float*)d_in[8];
    const float* p_lin_b  = (const float*)d_in[9];
    const float* p_att_w  = (const float*)d_in[10];
    const float* p_att_b  = (const float*)d_in[11];
    const float* p_le1_w  = (const float*)d_in[12];
    const float* p_le1_b  = (const float*)d_in[13];
    const float* p_le2_w  = (const float*)d_in[14];
    const float* p_le3_w  = (const float*)d_in[15];
    const float* p_le3_b  = (const float*)d_in[16];
    const float* lin1_w   = (const float*)d_in[17];
    const float* lin1_b   = (const float*)d_in[18];
    const float* lin2_w   = (const float*)d_in[19];
    const float* lin2_b   = (const float*)d_in[20];
    float* out = (float*)d_out;

    const int E = in_sizes[1] / 2;   // 32768

    // workspace layout (memset region first: Mb1|Rb1|xsf|Mb2|Mb3)
    u32*   Mb1 = (u32*)d_ws;                  //  8192
    u32*   Rb1 = Mb1 + 8192;                  //  8192
    float* xsf = (float*)(Rb1 + 8192);        // 10240
    u32*   Mb2 = (u32*)(xsf + 10240);         //  8192
    u32*   Mb3 = Mb2 + 8192;                  //  8192
    float* qaw = (float*)(Mb3 + 8192);        //  2048
    float* xaw = qaw + 2048;                  //  2048
    float* vbuf = xaw + 2048;                 //  256 (2 x 128)
    float* c0buf = vbuf + 256;                //  2 (+pad 2)
    float* agg = c0buf + 4;                   // 262144 (aliased as T_ws in pools)
    float* hA  = agg + 262144;                // 262144
    float* hB  = hA  + 262144;                // 262144
    float* Scm = hB  + 262144;                // 262144
    float* xnw = Scm + 262144;                // 262144
    float* Ssr = xnw + 262144;                // 16*128*112 = 229376
    float* SsT = Ssr + 229376;                // 262144
    float* A2  = SsT + 262144;                // 169744
    float* A2T = A2  + 169744;                // 169744
    float* A3  = A2T + 169744;                // 110224
    float* A3T = A3  + 110224;                // 110224
    float* Tw  = agg;                         // alias: disjoint lifetime vs conv agg

    hipMemsetAsync(d_ws, 0, (8192 + 8192 + 10240 + 8192 + 8192) * 4, stream);
    k_build<<<(E + 255) / 256, 256, 0, stream>>>(ei, Mb1, Rb1, E);
    k_prep<<<2, 128, 0, stream>>>(p_lin_w, p_lin_b, p_att_w, vbuf, c0buf);

    // conv0: Cin=64 (G=16 rows/block)
    k_agg_mask<<<dim3(16, 4), 512, 0, stream>>>(x, Mb1, agg, 128, 64);
    k_out<64><<<dim3(16, 8), 512, 0, stream>>>(x, agg, c0_wrel, c0_brel, c0_wroot,
                                               hA, xsf + 0 * 2048, 128);
    // conv1 (Cin=128, G=8 rows/block)
    k_agg_mask<<<dim3(16, 8), 512, 0, stream>>>(hA, Mb1, agg, 128, 128);
    k_out<128><<<dim3(16, 16), 512, 0, stream>>>(hA, agg, cw_rel, cb_rel, cw_root,
                                                 hB, xsf + 1 * 2048, 128);
    // pool1: n=128 -> k=103 (kpad=112)
    k_attn<<<dim3(16, 8), 512, 0, stream>>>(hB, Mb1, vbuf, c0buf, p_att_w, qaw, xaw, 128);
    k_soft<<<dim3(16, 16), 512, 0, stream>>>(Mb1, qaw, xaw, p_att_b, Scm, 128);
    k_xnew<<<dim3(16, 8), 512, 0, stream>>>(Scm, hB, xnw, 128);
    k_fit<<<16, 512, 0, stream>>>(xnw, Mb1, Scm,
                                  p_le1_w, p_le1_b, p_le2_w, p_le3_w, p_le3_b,
                                  hA, Ssr, SsT, 128, 103, 112);
    k_T_mask<<<dim3(16, 7), 512, 0, stream>>>(Rb1, Ssr, Tw, 128, 103, 112);
    k_A2<<<dim3(16, 21), 512, 0, stream>>>(SsT, Tw, A2, A2T, Mb2, 128, 103, 112);
    // conv2
    k_agg_dense<<<dim3(16, 7), 512, 0, stream>>>(hA, A2T, Mb2, agg, 103);
    k_out<128><<<dim3(16, 13), 512, 0, stream>>>(hA, agg, cw_rel + 16384, cb_rel + 128,
                                                 cw_root + 16384, hB, xsf + 2 * 2048, 103);
    // conv3
    k_agg_dense<<<dim3(16, 7), 512, 0, stream>>>(hB, A2T, Mb2, agg, 103);
    k_out<128><<<dim3(16, 13), 512, 0, stream>>>(hB, agg, cw_rel + 2 * 16384, cb_rel + 2 * 128,
                                                 cw_root + 2 * 16384, hA, xsf + 3 * 2048, 103);
    // pool2: n=103 -> k=83 (kpad=96)
    k_attn<<<dim3(16, 7), 512, 0, stream>>>(hA, Mb2, vbuf + 128, c0buf + 1,
                                            p_att_w + 256, qaw, xaw, 103);
    k_soft<<<dim3(16, 13), 512, 0, stream>>>(Mb2, qaw, xaw, p_att_b + 1, Scm, 103);
    k_xnew<<<dim3(16, 7), 512, 0, stream>>>(Scm, hA, xnw, 103);
    k_fit<<<16, 512, 0, stream>>>(xnw, Mb2, Scm,
                                  p_le1_w + 128, p_le1_b + 1, p_le2_w + 128,
                                  p_le3_w + 128, p_le3_b + 1,
                                  hB, Ssr, SsT, 103, 83, 96);
    k_T_dense<<<dim3(16, 5), 512, 0, stream>>>(A2, Ssr, Tw, 103, 83, 96);
    k_A2<<<dim3(16, 14), 512, 0, stream>>>(SsT, Tw, A3, A3T, Mb3, 103, 83, 96);
    // conv4
    k_agg_dense<<<dim3(16, 6), 512, 0, stream>>>(hB, A3T, Mb3, agg, 83);
    k_out<128><<<dim3(16, 11), 512, 0, stream>>>(hB, agg, cw_rel + 3 * 16384, cb_rel + 3 * 128,
                                                 cw_root + 3 * 16384, hA, xsf + 4 * 2048, 83);

    k_final<<<16, 256, 0, stream>>>(xsf, lin1_w, lin1_b, lin2_w, lin2_b, out);
}

// Round 9
// 555.196 us; speedup vs baseline: 1.3581x; 1.3581x over previous
//
#include <hip/hip_runtime.h>

#define NEG_SLOPE 0.2f
typedef unsigned int u32;

// ------------------------------------------------------------ build bitmasks
__global__ __launch_bounds__(256) void k_build(const int* __restrict__ ei,
                                               u32* __restrict__ Mb,
                                               u32* __restrict__ Rb, int E)
{
    int e = blockIdx.x * 256 + threadIdx.x;
    if (e >= E) return;
    int s = ei[e], d = ei[E + e];
    int g = s >> 7, ls = s & 127, ld = d & 127;
    atomicOr(&Mb[(g * 128 + ld) * 4 + (ls >> 5)], 1u << (ls & 31));  // col mask (in-edges)
    atomicOr(&Rb[(g * 128 + ls) * 4 + (ld >> 5)], 1u << (ld & 31));  // row mask (out-edges)
}

// ------------------------------------- precompute v = lin_w^T a_q, c0 = lin_b·a_q
__global__ __launch_bounds__(128) void k_prep(
    const float* __restrict__ lin_w, const float* __restrict__ lin_b,
    const float* __restrict__ att_w,
    float* __restrict__ v_out, float* __restrict__ c0_out)
{
    const int p = blockIdx.x;
    const float* lw = lin_w + p * 16384;
    const float* lb = lin_b + p * 128;
    const float* aw = att_w + p * 256;
    const int c = threadIdx.x;
    float s = 0.f;
    for (int c2 = 0; c2 < 128; ++c2) s += aw[c2] * lw[c2 * 128 + c];
    v_out[p * 128 + c] = s;
    if (c < 64) {
        float s0 = aw[c] * lb[c] + aw[c + 64] * lb[c + 64];
        for (int off = 32; off; off >>= 1) s0 += __shfl_xor(s0, off);
        if (c == 0) c0_out[p] = s0;
    }
}

// --------------------------------------------- agg = (A^T h)/deg, binary A
__global__ __launch_bounds__(512) void k_agg_mask(
    const float* __restrict__ h, const u32* __restrict__ Mb,
    float* __restrict__ agg, int n, int Cin)
{
    const int g = blockIdx.x;
    const int q4 = Cin >> 2;
    int idx = blockIdx.y * 512 + threadIdx.x;
    if (idx >= n * q4) return;
    int j = idx / q4, c4 = (idx - j * q4) << 2;
    const u32* m = Mb + (g * 128 + j) * 4;
    u32 m0 = m[0], m1 = m[1], m2 = m[2], m3 = m[3];
    float dv = fmaxf((float)(__popc(m0) + __popc(m1) + __popc(m2) + __popc(m3)), 1.0f);
    const float* hg = h + (size_t)g * n * Cin + c4;
    float sx = 0.f, sy = 0.f, sz = 0.f, sw = 0.f;
    u32 wds[4] = { m0, m1, m2, m3 };
    #pragma unroll
    for (int ww = 0; ww < 4; ++ww) {
        u32 u = wds[ww];
        while (u) {
            int i = (ww << 5) + __ffs(u) - 1; u &= u - 1u;
            float4 hv = *(const float4*)(hg + (size_t)i * Cin);
            sx += hv.x; sy += hv.y; sz += hv.z; sw += hv.w;
        }
    }
    float4 o; o.x = sx / dv; o.y = sy / dv; o.z = sz / dv; o.w = sw / dv;
    *(float4*)(agg + ((size_t)g * n + j) * Cin + c4) = o;
}

// --------------------------------------------- agg = (A^T h)/deg, dense A via A^T
__global__ __launch_bounds__(512) void k_agg_dense(
    const float* __restrict__ h, const float* __restrict__ AT,
    const u32* __restrict__ Mb, float* __restrict__ agg, int n)
{
    const int C = 128;
    const int g = blockIdx.x;
    int idx = blockIdx.y * 512 + threadIdx.x;
    if (idx >= n * 32) return;
    int j = idx >> 5, c4 = (idx & 31) << 2;
    const u32* m = Mb + (g * 128 + j) * 4;
    float dv = fmaxf((float)(__popc(m[0]) + __popc(m[1]) + __popc(m[2]) + __popc(m[3])), 1.0f);
    const float* Aj = AT + ((size_t)g * n + j) * n;     // AT[j][i] = A[i][j]
    const float* hg = h + (size_t)g * n * C + c4;
    float sx = 0.f, sy = 0.f, sz = 0.f, sw = 0.f;
    for (int i = 0; i < n; ++i) {
        float a = Aj[i];
        float4 hv = *(const float4*)(hg + (size_t)i * C);
        sx += a * hv.x; sy += a * hv.y; sz += a * hv.z; sw += a * hv.w;
    }
    float4 o; o.x = sx / dv; o.y = sy / dv; o.z = sz / dv; o.w = sw / dv;
    *(float4*)(agg + ((size_t)g * n + j) * C + c4) = o;
}

// ------- out = relu(agg@wrel^T + brel + h@wroot^T), fused gpool partial sums
// group of L=Cin/2 lanes owns one row; X in registers; no inner barriers.
// c2 unrolled x4: 4 W-loads in flight + 4 interleaved reduce chains (ILP).
template<int CIN>
__global__ __launch_bounds__(512) void k_out(
    const float* __restrict__ h, const float* __restrict__ agg,
    const float* __restrict__ wrel, const float* __restrict__ brel,
    const float* __restrict__ wroot,
    float* __restrict__ h_out, float* __restrict__ xs,
    int n)
{
    constexpr int L = CIN >> 1;        // lanes per row-group (32 or 64)
    constexpr int G = 512 / L;         // rows per block (16 or 8)
    constexpr int HALF = L >> 1;       // float4 slots per operand
    const int g = blockIdx.x;
    const int gg = threadIdx.x / L;
    const int l  = threadIdx.x % L;
    const int jg = blockIdx.y * G + gg;
    __shared__ float tile[G * 128];

    if (jg < n) {
        const float* xsrc = (l < HALF)
            ? (agg + ((size_t)g * n + jg) * CIN + (l << 2))
            : (h   + ((size_t)g * n + jg) * CIN + ((l - HALF) << 2));
        const float4 xv = *(const float4*)xsrc;
        const float* wbase = (l < HALF) ? (wrel + (l << 2))
                                        : (wroot + ((l - HALF) << 2));
        for (int c2 = 0; c2 < 128; c2 += 4) {
            float4 w0 = *(const float4*)(wbase + (size_t)(c2 + 0) * CIN);
            float4 w1 = *(const float4*)(wbase + (size_t)(c2 + 1) * CIN);
            float4 w2 = *(const float4*)(wbase + (size_t)(c2 + 2) * CIN);
            float4 w3 = *(const float4*)(wbase + (size_t)(c2 + 3) * CIN);
            float a0 = xv.x * w0.x + xv.y * w0.y + xv.z * w0.z + xv.w * w0.w;
            float a1 = xv.x * w1.x + xv.y * w1.y + xv.z * w1.z + xv.w * w1.w;
            float a2 = xv.x * w2.x + xv.y * w2.y + xv.z * w2.z + xv.w * w2.w;
            float a3 = xv.x * w3.x + xv.y * w3.y + xv.z * w3.z + xv.w * w3.w;
            #pragma unroll
            for (int off = L >> 1; off; off >>= 1) {
                a0 += __shfl_xor(a0, off, L);
                a1 += __shfl_xor(a1, off, L);
                a2 += __shfl_xor(a2, off, L);
                a3 += __shfl_xor(a3, off, L);
            }
            if (l == 0) {
                tile[gg * 128 + c2 + 0] = fmaxf(a0 + brel[c2 + 0], 0.0f);
                tile[gg * 128 + c2 + 1] = fmaxf(a1 + brel[c2 + 1], 0.0f);
                tile[gg * 128 + c2 + 2] = fmaxf(a2 + brel[c2 + 2], 0.0f);
                tile[gg * 128 + c2 + 3] = fmaxf(a3 + brel[c2 + 3], 0.0f);
            }
        }
    } else {
        for (int c2 = l; c2 < 128; c2 += L) tile[gg * 128 + c2] = 0.0f;
    }
    __syncthreads();

    const int tid = threadIdx.x;
    // coalesced h_out writes
    for (int idx = tid; idx < G * 32; idx += 512) {
        int r = idx >> 5, c4 = (idx & 31) << 2;
        int j2 = blockIdx.y * G + r;
        if (j2 < n)
            *(float4*)(h_out + ((size_t)g * n + j2) * 128 + c4) =
                *(const float4*)(tile + r * 128 + c4);
    }
    // gpool partials: one atomic per column per block
    if (tid < 128) {
        float s = 0.f;
        #pragma unroll
        for (int r = 0; r < G; ++r) s += tile[r * 128 + tid];
        atomicAdd(&xs[g * 128 + tid], s / (float)n);
    }
}

// ------------- pool stage 1a: qa[j] = maskedColMax(h)·v + c0 ; xa[i] = h[i]·a_x
__global__ __launch_bounds__(512) void k_attn(
    const float* __restrict__ h, const u32* __restrict__ Mb_g,
    const float* __restrict__ v_g, const float* __restrict__ c0_g,
    const float* __restrict__ att_w,
    float* __restrict__ qa_g, float* __restrict__ xa_g, int n)
{
    const int g = blockIdx.x;
    const int tid = threadIdx.x;
    const int hw = tid >> 5, ln = tid & 31;
    const float* hg = h + (size_t)g * n * 128;
    const int j = blockIdx.y * 16 + hw;
    if (j < n) {
        u32 m[4];
        m[0] = Mb_g[(g * 128 + j) * 4 + 0]; m[1] = Mb_g[(g * 128 + j) * 4 + 1];
        m[2] = Mb_g[(g * 128 + j) * 4 + 2]; m[3] = Mb_g[(g * 128 + j) * 4 + 3];
        m[j >> 5] |= 1u << (j & 31);                  // diagonal
        float4 mx = make_float4(-1e30f, -1e30f, -1e30f, -1e30f);
        #pragma unroll
        for (int ww = 0; ww < 4; ++ww) {
            u32 u = m[ww];
            while (u) {
                int i = (ww << 5) + __ffs(u) - 1; u &= u - 1u;
                float4 hv = *(const float4*)(hg + (size_t)i * 128 + ln * 4);
                mx.x = fmaxf(mx.x, hv.x); mx.y = fmaxf(mx.y, hv.y);
                mx.z = fmaxf(mx.z, hv.z); mx.w = fmaxf(mx.w, hv.w);
            }
        }
        float4 vv = *(const float4*)(v_g + ln * 4);
        float acc = mx.x * vv.x + mx.y * vv.y + mx.z * vv.z + mx.w * vv.w;
        #pragma unroll
        for (int off = 16; off; off >>= 1) acc += __shfl_xor(acc, off, 32);
        if (ln == 0) qa_g[g * 128 + j] = acc + c0_g[0];
    }
    const int i = blockIdx.y * 16 + hw;
    if (i < n) {
        float4 hv = *(const float4*)(hg + (size_t)i * 128 + ln * 4);
        float4 aw = *(const float4*)(att_w + 128 + ln * 4);
        float s = hv.x * aw.x + hv.y * aw.y + hv.z * aw.z + hv.w * aw.w;
        #pragma unroll
        for (int off = 16; off; off >>= 1) s += __shfl_xor(s, off, 32);
        if (ln == 0) xa_g[g * 128 + i] = s;
    }
}

// ------------- pool stage 1b: masked column softmax -> S_cm (wave per column)
__global__ __launch_bounds__(512) void k_soft(
    const u32* __restrict__ Mb_g, const float* __restrict__ qa_g,
    const float* __restrict__ xa_g, const float* __restrict__ att_bp,
    float* __restrict__ S_cm, int n)
{
    const int g = blockIdx.x;
    const int tid = threadIdx.x, lane = tid & 63, wid = tid >> 6;
    const int j = blockIdx.y * 8 + wid;
    if (j >= n) return;
    const float att_b = att_bp[0];
    u32 m[4];
    m[0] = Mb_g[(g * 128 + j) * 4 + 0]; m[1] = Mb_g[(g * 128 + j) * 4 + 1];
    m[2] = Mb_g[(g * 128 + j) * 4 + 2]; m[3] = Mb_g[(g * 128 + j) * 4 + 3];
    m[j >> 5] |= 1u << (j & 31);                      // diagonal
    const float qaj = qa_g[g * 128 + j];
    const int i0 = lane, i1 = lane + 64;
    const bool b0 = (i0 < n) && ((m[i0 >> 5] >> (i0 & 31)) & 1u);
    const bool b1 = (i1 < n) && ((m[i1 >> 5] >> (i1 & 31)) & 1u);
    float l0 = -1e30f, l1 = -1e30f;
    if (b0) { float t = xa_g[g * 128 + i0] + qaj + att_b; l0 = (t >= 0.f) ? t : NEG_SLOPE * t; }
    if (b1) { float t = xa_g[g * 128 + i1] + qaj + att_b; l1 = (t >= 0.f) ? t : NEG_SLOPE * t; }
    float mm = fmaxf(l0, l1);
    for (int off = 32; off; off >>= 1) mm = fmaxf(mm, __shfl_xor(mm, off));
    float e0 = b0 ? expf(l0 - mm) : 0.f;
    float e1 = b1 ? expf(l1 - mm) : 0.f;
    float s = e0 + e1;
    for (int off = 32; off; off >>= 1) s += __shfl_xor(s, off);
    float* Sj = S_cm + ((size_t)g * 128 + j) * 128;
    if (i0 < n) Sj[i0] = e0 / s;
    if (i1 < n) Sj[i1] = e1 / s;
}

// ---------------------------------------- pool stage 2: x_new = S_cm @ h
__global__ __launch_bounds__(512) void k_xnew(
    const float* __restrict__ S_cm, const float* __restrict__ h,
    float* __restrict__ xn, int n)
{
    const int g = blockIdx.x;
    int idx = blockIdx.y * 512 + threadIdx.x;
    if (idx >= n * 32) return;
    int j = idx >> 5, c4 = (idx & 31) << 2;
    const float* Sj = S_cm + ((size_t)g * 128 + j) * 128;
    const float* hg = h + (size_t)g * n * 128 + c4;
    float sx = 0.f, sy = 0.f, sz = 0.f, sw = 0.f;
    for (int i = 0; i < n; ++i) {
        float sv = Sj[i];
        float4 hv = *(const float4*)(hg + (size_t)i * 128);
        sx += sv * hv.x; sy += sv * hv.y; sz += sv * hv.z; sw += sv * hv.w;
    }
    float4 o; o.x = sx; o.y = sy; o.z = sz; o.w = sw;
    *(float4*)(xn + ((size_t)g * 128 + j) * 128 + c4) = o;
}

// ------------- pool stage 3: fitness, top-k, h_out, Sselr gathers
__global__ __launch_bounds__(512) void k_fit(
    const float* __restrict__ xn, const u32* __restrict__ Mb_g,
    const float* __restrict__ S_cm,
    const float* __restrict__ le1_w, const float* __restrict__ le1_bp,
    const float* __restrict__ le2_w, const float* __restrict__ le3_w,
    const float* __restrict__ le3_bp,
    float* __restrict__ h_out, float* __restrict__ Sselr, float* __restrict__ SselrT,
    int n, int k, int kpad)
{
    const int g = blockIdx.x;
    const float* xg = xn + (size_t)g * 128 * 128;
    __shared__ float a_s[128], b_s[128], c3_s[128], fit_s[128];
    __shared__ int perm_s[128];
    const int tid = threadIdx.x, lane = tid & 63, wid = tid >> 6;

    for (int j = wid; j < n; j += 8) {
        float x0 = xg[j * 128 + lane], x1 = xg[j * 128 + 64 + lane];
        float s1 = x0 * le1_w[lane] + x1 * le1_w[64 + lane];
        float s2 = x0 * le2_w[lane] + x1 * le2_w[64 + lane];
        float s3 = x0 * le3_w[lane] + x1 * le3_w[64 + lane];
        for (int off = 32; off; off >>= 1) {
            s1 += __shfl_xor(s1, off);
            s2 += __shfl_xor(s2, off);
            s3 += __shfl_xor(s3, off);
        }
        if (lane == 0) { a_s[j] = s1 + le1_bp[0]; b_s[j] = s2; c3_s[j] = s3; }
    }
    __syncthreads();
    for (int j = tid; j < n; j += 512) {
        u32 m[4];
        m[0] = Mb_g[(g * 128 + j) * 4 + 0]; m[1] = Mb_g[(g * 128 + j) * 4 + 1];
        m[2] = Mb_g[(g * 128 + j) * 4 + 2]; m[3] = Mb_g[(g * 128 + j) * 4 + 3];
        m[j >> 5] |= 1u << (j & 31);                  // diagonal
        float dv = (float)(__popc(m[0]) + __popc(m[1]) + __popc(m[2]) + __popc(m[3]));
        float s = 0.f;
        #pragma unroll
        for (int ww = 0; ww < 4; ++ww) {
            u32 u = m[ww];
            while (u) { int i = (ww << 5) + __ffs(u) - 1; u &= u - 1u; s += a_s[i]; }
        }
        float f = s - dv * b_s[j] + c3_s[j] + le3_bp[0];
        fit_s[j] = 1.0f / (1.0f + expf(-f));
    }
    __syncthreads();
    // top-k by rank (ties -> lower index, matches lax.top_k)
    for (int j = tid; j < n; j += 512) {
        float fj = fit_s[j];
        int r = 0;
        for (int j2 = 0; j2 < n; ++j2) {
            float f2 = fit_s[j2];
            if (f2 > fj || (f2 == fj && j2 < j)) ++r;
        }
        if (r < k) perm_s[r] = j;
    }
    __syncthreads();
    // h_out[r] = x_new[perm[r]] * fit[perm[r]]
    for (int idx = tid; idx < k * 32; idx += 512) {
        int r = idx >> 5, c4 = (idx & 31) << 2;
        int p = perm_s[r]; float f = fit_s[p];
        float4 v = *(const float4*)(xg + p * 128 + c4);
        v.x *= f; v.y *= f; v.z *= f; v.w *= f;
        *(float4*)(h_out + ((size_t)g * k + r) * 128 + c4) = v;
    }
    // SselrT[r][i] = S_cm[perm[r]][i]   (row gather, coalesced)
    for (int idx = tid; idx < k * 32; idx += 512) {
        int r = idx >> 5, c4 = (idx & 31) << 2;
        float4 v = *(const float4*)(S_cm + ((size_t)g * 128 + perm_s[r]) * 128 + c4);
        *(float4*)(SselrT + ((size_t)g * 128 + r) * 128 + c4) = v;
    }
    // Sselr[i][cc] = S_cm[perm[cc]][i]  (coalesced reads, scattered 4B writes)
    for (int idx = tid; idx < k * n; idx += 512) {
        int cc = idx / n, i = idx - cc * n;
        Sselr[((size_t)g * 128 + i) * kpad + cc] =
            S_cm[((size_t)g * 128 + perm_s[cc]) * 128 + i];
    }
}

// ---------------------------------------- pool stage 4: T = A_d @ S_sel
__global__ __launch_bounds__(512) void k_T_mask(
    const u32* __restrict__ Rb, const float* __restrict__ Sselr,
    float* __restrict__ T, int n, int k, int kpad)
{
    const int g = blockIdx.x;
    const int ccq = (k + 3) >> 2;
    int idx = blockIdx.y * 512 + threadIdx.x;
    if (idx >= n * ccq) return;
    int i = idx / ccq, c4 = (idx - i * ccq) << 2;
    u32 m[4];
    m[0] = Rb[(g * 128 + i) * 4 + 0]; m[1] = Rb[(g * 128 + i) * 4 + 1];
    m[2] = Rb[(g * 128 + i) * 4 + 2]; m[3] = Rb[(g * 128 + i) * 4 + 3];
    m[i >> 5] |= 1u << (i & 31);                      // diagonal
    float sx = 0.f, sy = 0.f, sz = 0.f, sw = 0.f;
    #pragma unroll
    for (int ww = 0; ww < 4; ++ww) {
        u32 u = m[ww];
        while (u) {
            int j = (ww << 5) + __ffs(u) - 1; u &= u - 1u;
            float4 v = *(const float4*)(Sselr + ((size_t)g * 128 + j) * kpad + c4);
            sx += v.x; sy += v.y; sz += v.z; sw += v.w;
        }
    }
    float4 o; o.x = sx; o.y = sy; o.z = sz; o.w = sw;
    *(float4*)(T + ((size_t)g * 128 + i) * kpad + c4) = o;
}

__global__ __launch_bounds__(512) void k_T_dense(
    const float* __restrict__ A, const float* __restrict__ Sselr,
    float* __restrict__ T, int n, int k, int kpad)
{
    const int g = blockIdx.x;
    const int ccq = (k + 3) >> 2;
    int idx = blockIdx.y * 512 + threadIdx.x;
    if (idx >= n * ccq) return;
    int i = idx / ccq, c4 = (idx - i * ccq) << 2;
    const float* Ai = A + ((size_t)g * n + i) * n;    // unit diag already present
    float sx = 0.f, sy = 0.f, sz = 0.f, sw = 0.f;
    for (int j = 0; j < n; ++j) {
        float a = Ai[j];
        float4 v = *(const float4*)(Sselr + ((size_t)g * 128 + j) * kpad + c4);
        sx += a * v.x; sy += a * v.y; sz += a * v.z; sw += a * v.w;
    }
    float4 o; o.x = sx; o.y = sy; o.z = sz; o.w = sw;
    *(float4*)(T + ((size_t)g * 128 + i) * kpad + c4) = o;
}

// ------------- pool stage 5: A2 = S_sel^T @ T (+diag, +transpose, +mask)
__global__ __launch_bounds__(512) void k_A2(
    const float* __restrict__ SselrT, const float* __restrict__ T,
    float* __restrict__ A_out, float* __restrict__ AT_out,
    u32* __restrict__ Mb_out, int n, int k, int kpad)
{
    const int g = blockIdx.x;
    int idx = blockIdx.y * 512 + threadIdx.x;
    if (idx >= k * k) return;
    int r = idx / k, cc = idx - r * k;
    const float* Sr = SselrT + ((size_t)g * 128 + r) * 128;
    const float* Tg = T + (size_t)g * 128 * kpad;
    float s = 0.f;
    for (int i = 0; i < n; ++i) s += Sr[i] * Tg[i * kpad + cc];
    float val = (r == cc) ? 1.0f : s;
    A_out[((size_t)g * k + r) * k + cc] = val;
    AT_out[((size_t)g * k + cc) * k + r] = val;
    if (val != 0.0f)
        atomicOr(&Mb_out[((size_t)g * 128 + cc) * 4 + (r >> 5)], 1u << (r & 31));
}

// ------------------------------------------------------------- classifier ---
__global__ __launch_bounds__(256) void k_final(
    const float* __restrict__ xs,     // [5][16][128]
    const float* __restrict__ w1, const float* __restrict__ b1,
    const float* __restrict__ w2, const float* __restrict__ b2,
    float* __restrict__ out)
{
    const int g = blockIdx.x;
    __shared__ float j_s[640];
    __shared__ float z1[128];
    const int tid = threadIdx.x, lane = tid & 63, wid = tid >> 6;  // 4 waves

    for (int idx = tid; idx < 640; idx += 256) {
        int t = idx >> 7, c = idx & 127;
        j_s[idx] = xs[t * 2048 + g * 128 + c];
    }
    __syncthreads();
    for (int c2 = wid; c2 < 128; c2 += 4) {
        const float* wrow = w1 + (size_t)c2 * 640;
        float s = 0.f;
        #pragma unroll
        for (int it = 0; it < 10; ++it) {
            int kk = it * 64 + lane;
            s += j_s[kk] * wrow[kk];
        }
        for (int off = 32; off; off >>= 1) s += __shfl_xor(s, off);
        if (lane == 0) z1[c2] = fmaxf(s + b1[c2], 0.0f);
    }
    __syncthreads();
    if (wid == 0) {
        float zv0 = z1[lane], zv1 = z1[lane + 64];
        float za = zv0 * w2[lane] + zv1 * w2[lane + 64];
        float zb = zv0 * w2[128 + lane] + zv1 * w2[192 + lane];
        for (int off = 32; off; off >>= 1) {
            za += __shfl_xor(za, off);
            zb += __shfl_xor(zb, off);
        }
        if (lane == 0) {
            za += b2[0]; zb += b2[1];
            float m = fmaxf(za, zb);
            float lse = m + logf(expf(za - m) + expf(zb - m));
            out[g * 2 + 0] = za - lse;
            out[g * 2 + 1] = zb - lse;
        }
    }
}

// ---------------------------------------------------------------------------
extern "C" void kernel_launch(void* const* d_in, const int* in_sizes, int n_in,
                              void* d_out, int out_size, void* d_ws, size_t ws_size,
                              hipStream_t stream)
{
    (void)n_in; (void)out_size; (void)ws_size;
    const float* x        = (const float*)d_in[0];
    const int*   ei       = (const int*)  d_in[1];
    const float* c0_wrel  = (const float*)d_in[2];
    const float* c0_brel  = (const float*)d_in[3];
    const float* c0_wroot = (const float*)d_in[4];
    const float* cw_rel   = (const float*)d_in[5];
    const float* cb_rel   = (const float*)d_in[6];
    const float* cw_root  = (const float*)d_in[7];
    const float* p_lin_w  = (const float*)d_in[8];
    const float* p_lin_b  = (const float*)d_in[9];
    const float* p_att_w  = (const float*)d_in[10];
    const float* p_att_b  = (const float*)d_in[11];
    const float* p_le1_w  = (const float*)d_in[12];
    const float* p_le1_b  = (const float*)d_in[13];
    const float* p_le2_w  = (const float*)d_in[14];
    const float* p_le3_w  = (const float*)d_in[15];
    const float* p_le3_b  = (const float*)d_in[16];
    const float* lin1_w   = (const float*)d_in[17];
    const float* lin1_b   = (const float*)d_in[18];
    const float* lin2_w   = (const float*)d_in[19];
    const float* lin2_b   = (const float*)d_in[20];
    float* out = (float*)d_out;

    const int E = in_sizes[1] / 2;   // 32768

    // workspace layout (memset region first: Mb1|Rb1|xsf|Mb2|Mb3)
    u32*   Mb1 = (u32*)d_ws;                  //  8192
    u32*   Rb1 = Mb1 + 8192;                  //  8192
    float* xsf = (float*)(Rb1 + 8192);        // 10240
    u32*   Mb2 = (u32*)(xsf + 10240);         //  8192
    u32*   Mb3 = Mb2 + 8192;                  //  8192
    float* qaw = (float*)(Mb3 + 8192);        //  2048
    float* xaw = qaw + 2048;                  //  2048
    float* vbuf = xaw + 2048;                 //  256 (2 x 128)
    float* c0buf = vbuf + 256;                //  2 (+pad 2)
    float* agg = c0buf + 4;                   // 262144 (aliased as T_ws in pools)
    float* hA  = agg + 262144;                // 262144
    float* hB  = hA  + 262144;                // 262144
    float* Scm = hB  + 262144;                // 262144
    float* xnw = Scm + 262144;                // 262144
    float* Ssr = xnw + 262144;                // 16*128*112 = 229376
    float* SsT = Ssr + 229376;                // 262144
    float* A2  = SsT + 262144;                // 169744
    float* A2T = A2  + 169744;                // 169744
    float* A3  = A2T + 169744;                // 110224
    float* A3T = A3  + 110224;                // 110224
    float* Tw  = agg;                         // alias: disjoint lifetime vs conv agg

    hipMemsetAsync(d_ws, 0, (8192 + 8192 + 10240 + 8192 + 8192) * 4, stream);
    k_build<<<(E + 255) / 256, 256, 0, stream>>>(ei, Mb1, Rb1, E);
    k_prep<<<2, 128, 0, stream>>>(p_lin_w, p_lin_b, p_att_w, vbuf, c0buf);

    // conv0: Cin=64 (G=16 rows/block)
    k_agg_mask<<<dim3(16, 4), 512, 0, stream>>>(x, Mb1, agg, 128, 64);
    k_out<64><<<dim3(16, 8), 512, 0, stream>>>(x, agg, c0_wrel, c0_brel, c0_wroot,
                                               hA, xsf + 0 * 2048, 128);
    // conv1 (Cin=128, G=8 rows/block)
    k_agg_mask<<<dim3(16, 8), 512, 0, stream>>>(hA, Mb1, agg, 128, 128);
    k_out<128><<<dim3(16, 16), 512, 0, stream>>>(hA, agg, cw_rel, cb_rel, cw_root,
                                                 hB, xsf + 1 * 2048, 128);
    // pool1: n=128 -> k=103 (kpad=112)
    k_attn<<<dim3(16, 8), 512, 0, stream>>>(hB, Mb1, vbuf, c0buf, p_att_w, qaw, xaw, 128);
    k_soft<<<dim3(16, 16), 512, 0, stream>>>(Mb1, qaw, xaw, p_att_b, Scm, 128);
    k_xnew<<<dim3(16, 8), 512, 0, stream>>>(Scm, hB, xnw, 128);
    k_fit<<<16, 512, 0, stream>>>(xnw, Mb1, Scm,
                                  p_le1_w, p_le1_b, p_le2_w, p_le3_w, p_le3_b,
                                  hA, Ssr, SsT, 128, 103, 112);
    k_T_mask<<<dim3(16, 7), 512, 0, stream>>>(Rb1, Ssr, Tw, 128, 103, 112);
    k_A2<<<dim3(16, 21), 512, 0, stream>>>(SsT, Tw, A2, A2T, Mb2, 128, 103, 112);
    // conv2
    k_agg_dense<<<dim3(16, 7), 512, 0, stream>>>(hA, A2T, Mb2, agg, 103);
    k_out<128><<<dim3(16, 13), 512, 0, stream>>>(hA, agg, cw_rel + 16384, cb_rel + 128,
                                                 cw_root + 16384, hB, xsf + 2 * 2048, 103);
    // conv3
    k_agg_dense<<<dim3(16, 7), 512, 0, stream>>>(hB, A2T, Mb2, agg, 103);
    k_out<128><<<dim3(16, 13), 512, 0, stream>>>(hB, agg, cw_rel + 2 * 16384, cb_rel + 2 * 128,
                                                 cw_root + 2 * 16384, hA, xsf + 3 * 2048, 103);
    // pool2: n=103 -> k=83 (kpad=96)
    k_attn<<<dim3(16, 7), 512, 0, stream>>>(hA, Mb2, vbuf + 128, c0buf + 1,
                                            p_att_w + 256, qaw, xaw, 103);
    k_soft<<<dim3(16, 13), 512, 0, stream>>>(Mb2, qaw, xaw, p_att_b + 1, Scm, 103);
    k_xnew<<<dim3(16, 7), 512, 0, stream>>>(Scm, hA, xnw, 103);
    k_fit<<<16, 512, 0, stream>>>(xnw, Mb2, Scm,
                                  p_le1_w + 128, p_le1_b + 1, p_le2_w + 128,
                                  p_le3_w + 128, p_le3_b + 1,
                                  hB, Ssr, SsT, 103, 83, 96);
    k_T_dense<<<dim3(16, 5), 512, 0, stream>>>(A2, Ssr, Tw, 103, 83, 96);
    k_A2<<<dim3(16, 14), 512, 0, stream>>>(SsT, Tw, A3, A3T, Mb3, 103, 83, 96);
    // conv4
    k_agg_dense<<<dim3(16, 6), 512, 0, stream>>>(hB, A3T, Mb3, agg, 83);
    k_out<128><<<dim3(16, 11), 512, 0, stream>>>(hB, agg, cw_rel + 3 * 16384, cb_rel + 3 * 128,
                                                 cw_root + 3 * 16384, hA, xsf + 4 * 2048, 83);

    k_final<<<16, 256, 0, stream>>>(xsf, lin1_w, lin1_b, lin2_w, lin2_b, out);
}

// Round 11
// 514.240 us; speedup vs baseline: 1.4662x; 1.0796x over previous
//
#include <hip/hip_runtime.h>

#define NEG_SLOPE 0.2f
typedef unsigned int u32;

// ------------------------------------------------------------ build bitmasks
__global__ __launch_bounds__(256) void k_build(const int* __restrict__ ei,
                                               u32* __restrict__ Mb,
                                               u32* __restrict__ Rb, int E)
{
    int e = blockIdx.x * 256 + threadIdx.x;
    if (e >= E) return;
    int s = ei[e], d = ei[E + e];
    int g = s >> 7, ls = s & 127, ld = d & 127;
    atomicOr(&Mb[(g * 128 + ld) * 4 + (ls >> 5)], 1u << (ls & 31));  // col mask (in-edges)
    atomicOr(&Rb[(g * 128 + ls) * 4 + (ld >> 5)], 1u << (ld & 31));  // row mask (out-edges)
}

// ------------------------------------- precompute v = lin_w^T a_q, c0 = lin_b·a_q
__global__ __launch_bounds__(128) void k_prep(
    const float* __restrict__ lin_w, const float* __restrict__ lin_b,
    const float* __restrict__ att_w,
    float* __restrict__ v_out, float* __restrict__ c0_out)
{
    const int p = blockIdx.x;
    const float* lw = lin_w + p * 16384;
    const float* lb = lin_b + p * 128;
    const float* aw = att_w + p * 256;
    const int c = threadIdx.x;
    float s = 0.f;
    for (int c2 = 0; c2 < 128; ++c2) s += aw[c2] * lw[c2 * 128 + c];
    v_out[p * 128 + c] = s;
    if (c < 64) {
        float s0 = aw[c] * lb[c] + aw[c + 64] * lb[c + 64];
        for (int off = 32; off; off >>= 1) s0 += __shfl_xor(s0, off);
        if (c == 0) c0_out[p] = s0;
    }
}

// ---- fused conv: agg in registers + relu(agg@wrel^T + brel + h@wroot^T) + gpool
// group of L=CIN/2 lanes owns one row. Lanes <HALF build agg slice (split
// across half-groups, combined via one shfl_xor); lanes >=HALF hold h slice.
// W loop: x4 unroll, 4 loads in flight, interleaved reduces. No inner barriers.
template<int CIN, bool DENSE>
__global__ __launch_bounds__(512) void k_conv(
    const float* __restrict__ h, const u32* __restrict__ Mb,
    const float* __restrict__ AT,
    const float* __restrict__ wrel, const float* __restrict__ brel,
    const float* __restrict__ wroot,
    float* __restrict__ h_out, float* __restrict__ xs,
    int n)
{
    constexpr int L = CIN >> 1;        // lanes per row-group (32 or 64)
    constexpr int G = 512 / L;         // rows per block (16 or 8)
    constexpr int HALF = L >> 1;       // float4 slots per operand
    const int g = blockIdx.x;
    const int gg = threadIdx.x / L;
    const int l  = threadIdx.x % L;
    const int jg = blockIdx.y * G + gg;
    __shared__ float tile[G * 128];

    if (jg < n) {
        const int slot = l & (HALF - 1);
        const int c4 = slot << 2;
        const float* hsrc = h + (size_t)g * n * CIN;
        const u32* mp = Mb + (g * 128 + jg) * 4;
        u32 m0 = mp[0], m1 = mp[1], m2 = mp[2], m3 = mp[3];
        float dv = fmaxf((float)(__popc(m0) + __popc(m1) + __popc(m2) + __popc(m3)), 1.0f);
        float4 acc = make_float4(0.f, 0.f, 0.f, 0.f);
        const float* hc = hsrc + c4;
        if constexpr (!DENSE) {
            // binary A: bit-iterate; lanes <HALF take words 0,1; >=HALF words 2,3
            u32 wa = (l < HALF) ? m0 : m2;
            u32 wb = (l < HALF) ? m1 : m3;
            const int ba = (l < HALF) ? 0 : 64;
            u32 u = wa;
            while (u) {
                int i = ba + __ffs(u) - 1; u &= u - 1u;
                float4 v = *(const float4*)(hc + (size_t)i * CIN);
                acc.x += v.x; acc.y += v.y; acc.z += v.z; acc.w += v.w;
            }
            u = wb;
            while (u) {
                int i = ba + 32 + __ffs(u) - 1; u &= u - 1u;
                float4 v = *(const float4*)(hc + (size_t)i * CIN);
                acc.x += v.x; acc.y += v.y; acc.z += v.z; acc.w += v.w;
            }
        } else {
            // weighted A via AT row; lanes <HALF take [0,n/2), >=HALF [n/2,n)
            const float* Aj = AT + ((size_t)g * n + jg) * n;
            const int ibeg = (l < HALF) ? 0 : (n >> 1);
            const int iend = (l < HALF) ? (n >> 1) : n;
            for (int i = ibeg; i < iend; ++i) {
                float a = Aj[i];
                float4 v = *(const float4*)(hc + (size_t)i * CIN);
                acc.x += a * v.x; acc.y += a * v.y;
                acc.z += a * v.z; acc.w += a * v.w;
            }
        }
        // combine the two half-group partial sums
        acc.x += __shfl_xor(acc.x, HALF, L);
        acc.y += __shfl_xor(acc.y, HALF, L);
        acc.z += __shfl_xor(acc.z, HALF, L);
        acc.w += __shfl_xor(acc.w, HALF, L);

        float4 xv;
        if (l < HALF) {
            xv.x = acc.x / dv; xv.y = acc.y / dv;
            xv.z = acc.z / dv; xv.w = acc.w / dv;
        } else {
            xv = *(const float4*)(hsrc + (size_t)jg * CIN + c4);
        }

        const float* wbase = (l < HALF) ? (wrel + (l << 2))
                                        : (wroot + ((l - HALF) << 2));
        for (int c2 = 0; c2 < 128; c2 += 4) {
            float4 w0 = *(const float4*)(wbase + (size_t)(c2 + 0) * CIN);
            float4 w1 = *(const float4*)(wbase + (size_t)(c2 + 1) * CIN);
            float4 w2 = *(const float4*)(wbase + (size_t)(c2 + 2) * CIN);
            float4 w3 = *(const float4*)(wbase + (size_t)(c2 + 3) * CIN);
            float a0 = xv.x * w0.x + xv.y * w0.y + xv.z * w0.z + xv.w * w0.w;
            float a1 = xv.x * w1.x + xv.y * w1.y + xv.z * w1.z + xv.w * w1.w;
            float a2 = xv.x * w2.x + xv.y * w2.y + xv.z * w2.z + xv.w * w2.w;
            float a3 = xv.x * w3.x + xv.y * w3.y + xv.z * w3.z + xv.w * w3.w;
            #pragma unroll
            for (int off = L >> 1; off; off >>= 1) {
                a0 += __shfl_xor(a0, off, L);
                a1 += __shfl_xor(a1, off, L);
                a2 += __shfl_xor(a2, off, L);
                a3 += __shfl_xor(a3, off, L);
            }
            if (l == 0) {
                tile[gg * 128 + c2 + 0] = fmaxf(a0 + brel[c2 + 0], 0.0f);
                tile[gg * 128 + c2 + 1] = fmaxf(a1 + brel[c2 + 1], 0.0f);
                tile[gg * 128 + c2 + 2] = fmaxf(a2 + brel[c2 + 2], 0.0f);
                tile[gg * 128 + c2 + 3] = fmaxf(a3 + brel[c2 + 3], 0.0f);
            }
        }
    } else {
        for (int c2 = l; c2 < 128; c2 += L) tile[gg * 128 + c2] = 0.0f;
    }
    __syncthreads();

    const int tid = threadIdx.x;
    // coalesced h_out writes
    for (int idx = tid; idx < G * 32; idx += 512) {
        int r = idx >> 5, c4 = (idx & 31) << 2;
        int j2 = blockIdx.y * G + r;
        if (j2 < n)
            *(float4*)(h_out + ((size_t)g * n + j2) * 128 + c4) =
                *(const float4*)(tile + r * 128 + c4);
    }
    // gpool partials: one atomic per column per block
    if (tid < 128) {
        float s = 0.f;
        #pragma unroll
        for (int r = 0; r < G; ++r) s += tile[r * 128 + tid];
        atomicAdd(&xs[g * 128 + tid], s / (float)n);
    }
}

// ------------- pool stage 1a: qa[j] = maskedColMax(h)·v + c0 ; xa[i] = h[i]·a_x
__global__ __launch_bounds__(512) void k_attn(
    const float* __restrict__ h, const u32* __restrict__ Mb_g,
    const float* __restrict__ v_g, const float* __restrict__ c0_g,
    const float* __restrict__ att_w,
    float* __restrict__ qa_g, float* __restrict__ xa_g, int n)
{
    const int g = blockIdx.x;
    const int tid = threadIdx.x;
    const int hw = tid >> 5, ln = tid & 31;
    const float* hg = h + (size_t)g * n * 128;
    const int j = blockIdx.y * 16 + hw;
    if (j < n) {
        u32 m[4];
        m[0] = Mb_g[(g * 128 + j) * 4 + 0]; m[1] = Mb_g[(g * 128 + j) * 4 + 1];
        m[2] = Mb_g[(g * 128 + j) * 4 + 2]; m[3] = Mb_g[(g * 128 + j) * 4 + 3];
        m[j >> 5] |= 1u << (j & 31);                  // diagonal
        float4 mx = make_float4(-1e30f, -1e30f, -1e30f, -1e30f);
        #pragma unroll
        for (int ww = 0; ww < 4; ++ww) {
            u32 u = m[ww];
            while (u) {
                int i = (ww << 5) + __ffs(u) - 1; u &= u - 1u;
                float4 hv = *(const float4*)(hg + (size_t)i * 128 + ln * 4);
                mx.x = fmaxf(mx.x, hv.x); mx.y = fmaxf(mx.y, hv.y);
                mx.z = fmaxf(mx.z, hv.z); mx.w = fmaxf(mx.w, hv.w);
            }
        }
        float4 vv = *(const float4*)(v_g + ln * 4);
        float acc = mx.x * vv.x + mx.y * vv.y + mx.z * vv.z + mx.w * vv.w;
        #pragma unroll
        for (int off = 16; off; off >>= 1) acc += __shfl_xor(acc, off, 32);
        if (ln == 0) qa_g[g * 128 + j] = acc + c0_g[0];
    }
    const int i = blockIdx.y * 16 + hw;
    if (i < n) {
        float4 hv = *(const float4*)(hg + (size_t)i * 128 + ln * 4);
        float4 aw = *(const float4*)(att_w + 128 + ln * 4);
        float s = hv.x * aw.x + hv.y * aw.y + hv.z * aw.z + hv.w * aw.w;
        #pragma unroll
        for (int off = 16; off; off >>= 1) s += __shfl_xor(s, off, 32);
        if (ln == 0) xa_g[g * 128 + i] = s;
    }
}

// ------------- pool stage 1b: masked column softmax -> S_cm (wave per column)
__global__ __launch_bounds__(512) void k_soft(
    const u32* __restrict__ Mb_g, const float* __restrict__ qa_g,
    const float* __restrict__ xa_g, const float* __restrict__ att_bp,
    float* __restrict__ S_cm, int n)
{
    const int g = blockIdx.x;
    const int tid = threadIdx.x, lane = tid & 63, wid = tid >> 6;
    const int j = blockIdx.y * 8 + wid;
    if (j >= n) return;
    const float att_b = att_bp[0];
    u32 m[4];
    m[0] = Mb_g[(g * 128 + j) * 4 + 0]; m[1] = Mb_g[(g * 128 + j) * 4 + 1];
    m[2] = Mb_g[(g * 128 + j) * 4 + 2]; m[3] = Mb_g[(g * 128 + j) * 4 + 3];
    m[j >> 5] |= 1u << (j & 31);                      // diagonal
    const float qaj = qa_g[g * 128 + j];
    const int i0 = lane, i1 = lane + 64;
    const bool b0 = (i0 < n) && ((m[i0 >> 5] >> (i0 & 31)) & 1u);
    const bool b1 = (i1 < n) && ((m[i1 >> 5] >> (i1 & 31)) & 1u);
    float l0 = -1e30f, l1 = -1e30f;
    if (b0) { float t = xa_g[g * 128 + i0] + qaj + att_b; l0 = (t >= 0.f) ? t : NEG_SLOPE * t; }
    if (b1) { float t = xa_g[g * 128 + i1] + qaj + att_b; l1 = (t >= 0.f) ? t : NEG_SLOPE * t; }
    float mm = fmaxf(l0, l1);
    for (int off = 32; off; off >>= 1) mm = fmaxf(mm, __shfl_xor(mm, off));
    float e0 = b0 ? expf(l0 - mm) : 0.f;
    float e1 = b1 ? expf(l1 - mm) : 0.f;
    float s = e0 + e1;
    for (int off = 32; off; off >>= 1) s += __shfl_xor(s, off);
    float* Sj = S_cm + ((size_t)g * 128 + j) * 128;
    if (i0 < n) Sj[i0] = e0 / s;
    if (i1 < n) Sj[i1] = e1 / s;
}

// ---------------------------------------- pool stage 2: x_new = S_cm @ h
__global__ __launch_bounds__(512) void k_xnew(
    const float* __restrict__ S_cm, const float* __restrict__ h,
    float* __restrict__ xn, int n)
{
    const int g = blockIdx.x;
    int idx = blockIdx.y * 512 + threadIdx.x;
    if (idx >= n * 32) return;
    int j = idx >> 5, c4 = (idx & 31) << 2;
    const float* Sj = S_cm + ((size_t)g * 128 + j) * 128;
    const float* hg = h + (size_t)g * n * 128 + c4;
    float sx = 0.f, sy = 0.f, sz = 0.f, sw = 0.f;
    for (int i = 0; i < n; ++i) {
        float sv = Sj[i];
        float4 hv = *(const float4*)(hg + (size_t)i * 128);
        sx += sv * hv.x; sy += sv * hv.y; sz += sv * hv.z; sw += sv * hv.w;
    }
    float4 o; o.x = sx; o.y = sy; o.z = sz; o.w = sw;
    *(float4*)(xn + ((size_t)g * 128 + j) * 128 + c4) = o;
}

// ------------- pool stage 3: fitness, top-k, h_out, Sselr gathers
__global__ __launch_bounds__(512) void k_fit(
    const float* __restrict__ xn, const u32* __restrict__ Mb_g,
    const float* __restrict__ S_cm,
    const float* __restrict__ le1_w, const float* __restrict__ le1_bp,
    const float* __restrict__ le2_w, const float* __restrict__ le3_w,
    const float* __restrict__ le3_bp,
    float* __restrict__ h_out, float* __restrict__ Sselr, float* __restrict__ SselrT,
    int n, int k, int kpad)
{
    const int g = blockIdx.x;
    const float* xg = xn + (size_t)g * 128 * 128;
    __shared__ float a_s[128], b_s[128], c3_s[128], fit_s[128];
    __shared__ int perm_s[128];
    const int tid = threadIdx.x, lane = tid & 63, wid = tid >> 6;

    for (int j = wid; j < n; j += 8) {
        float x0 = xg[j * 128 + lane], x1 = xg[j * 128 + 64 + lane];
        float s1 = x0 * le1_w[lane] + x1 * le1_w[64 + lane];
        float s2 = x0 * le2_w[lane] + x1 * le2_w[64 + lane];
        float s3 = x0 * le3_w[lane] + x1 * le3_w[64 + lane];
        for (int off = 32; off; off >>= 1) {
            s1 += __shfl_xor(s1, off);
            s2 += __shfl_xor(s2, off);
            s3 += __shfl_xor(s3, off);
        }
        if (lane == 0) { a_s[j] = s1 + le1_bp[0]; b_s[j] = s2; c3_s[j] = s3; }
    }
    __syncthreads();
    for (int j = tid; j < n; j += 512) {
        u32 m[4];
        m[0] = Mb_g[(g * 128 + j) * 4 + 0]; m[1] = Mb_g[(g * 128 + j) * 4 + 1];
        m[2] = Mb_g[(g * 128 + j) * 4 + 2]; m[3] = Mb_g[(g * 128 + j) * 4 + 3];
        m[j >> 5] |= 1u << (j & 31);                  // diagonal
        float dv = (float)(__popc(m[0]) + __popc(m[1]) + __popc(m[2]) + __popc(m[3]));
        float s = 0.f;
        #pragma unroll
        for (int ww = 0; ww < 4; ++ww) {
            u32 u = m[ww];
            while (u) { int i = (ww << 5) + __ffs(u) - 1; u &= u - 1u; s += a_s[i]; }
        }
        float f = s - dv * b_s[j] + c3_s[j] + le3_bp[0];
        fit_s[j] = 1.0f / (1.0f + expf(-f));
    }
    __syncthreads();
    // top-k by rank (ties -> lower index, matches lax.top_k)
    for (int j = tid; j < n; j += 512) {
        float fj = fit_s[j];
        int r = 0;
        for (int j2 = 0; j2 < n; ++j2) {
            float f2 = fit_s[j2];
            if (f2 > fj || (f2 == fj && j2 < j)) ++r;
        }
        if (r < k) perm_s[r] = j;
    }
    __syncthreads();
    // h_out[r] = x_new[perm[r]] * fit[perm[r]]
    for (int idx = tid; idx < k * 32; idx += 512) {
        int r = idx >> 5, c4 = (idx & 31) << 2;
        int p = perm_s[r]; float f = fit_s[p];
        float4 v = *(const float4*)(xg + p * 128 + c4);
        v.x *= f; v.y *= f; v.z *= f; v.w *= f;
        *(float4*)(h_out + ((size_t)g * k + r) * 128 + c4) = v;
    }
    // SselrT[r][i] = S_cm[perm[r]][i]   (row gather, coalesced)
    for (int idx = tid; idx < k * 32; idx += 512) {
        int r = idx >> 5, c4 = (idx & 31) << 2;
        float4 v = *(const float4*)(S_cm + ((size_t)g * 128 + perm_s[r]) * 128 + c4);
        *(float4*)(SselrT + ((size_t)g * 128 + r) * 128 + c4) = v;
    }
    // Sselr[i][cc] = S_cm[perm[cc]][i]  (coalesced reads, scattered 4B writes)
    for (int idx = tid; idx < k * n; idx += 512) {
        int cc = idx / n, i = idx - cc * n;
        Sselr[((size_t)g * 128 + i) * kpad + cc] =
            S_cm[((size_t)g * 128 + perm_s[cc]) * 128 + i];
    }
}

// ---------------------------------------- pool stage 4: T = A_d @ S_sel
__global__ __launch_bounds__(512) void k_T_mask(
    const u32* __restrict__ Rb, const float* __restrict__ Sselr,
    float* __restrict__ T, int n, int k, int kpad)
{
    const int g = blockIdx.x;
    const int ccq = (k + 3) >> 2;
    int idx = blockIdx.y * 512 + threadIdx.x;
    if (idx >= n * ccq) return;
    int i = idx / ccq, c4 = (idx - i * ccq) << 2;
    u32 m[4];
    m[0] = Rb[(g * 128 + i) * 4 + 0]; m[1] = Rb[(g * 128 + i) * 4 + 1];
    m[2] = Rb[(g * 128 + i) * 4 + 2]; m[3] = Rb[(g * 128 + i) * 4 + 3];
    m[i >> 5] |= 1u << (i & 31);                      // diagonal
    float sx = 0.f, sy = 0.f, sz = 0.f, sw = 0.f;
    #pragma unroll
    for (int ww = 0; ww < 4; ++ww) {
        u32 u = m[ww];
        while (u) {
            int j = (ww << 5) + __ffs(u) - 1; u &= u - 1u;
            float4 v = *(const float4*)(Sselr + ((size_t)g * 128 + j) * kpad + c4);
            sx += v.x; sy += v.y; sz += v.z; sw += v.w;
        }
    }
    float4 o; o.x = sx; o.y = sy; o.z = sz; o.w = sw;
    *(float4*)(T + ((size_t)g * 128 + i) * kpad + c4) = o;
}

__global__ __launch_bounds__(512) void k_T_dense(
    const float* __restrict__ A, const float* __restrict__ Sselr,
    float* __restrict__ T, int n, int k, int kpad)
{
    const int g = blockIdx.x;
    const int ccq = (k + 3) >> 2;
    int idx = blockIdx.y * 512 + threadIdx.x;
    if (idx >= n * ccq) return;
    int i = idx / ccq, c4 = (idx - i * ccq) << 2;
    const float* Ai = A + ((size_t)g * n + i) * n;    // unit diag already present
    float sx = 0.f, sy = 0.f, sz = 0.f, sw = 0.f;
    for (int j = 0; j < n; ++j) {
        float a = Ai[j];
        float4 v = *(const float4*)(Sselr + ((size_t)g * 128 + j) * kpad + c4);
        sx += a * v.x; sy += a * v.y; sz += a * v.z; sw += a * v.w;
    }
    float4 o; o.x = sx; o.y = sy; o.z = sz; o.w = sw;
    *(float4*)(T + ((size_t)g * 128 + i) * kpad + c4) = o;
}

// ------------- pool stage 5: A2 = S_sel^T @ T (+diag, +transpose, +mask)
__global__ __launch_bounds__(512) void k_A2(
    const float* __restrict__ SselrT, const float* __restrict__ T,
    float* __restrict__ A_out, float* __restrict__ AT_out,
    u32* __restrict__ Mb_out, int n, int k, int kpad)
{
    const int g = blockIdx.x;
    int idx = blockIdx.y * 512 + threadIdx.x;
    if (idx >= k * k) return;
    int r = idx / k, cc = idx - r * k;
    const float* Sr = SselrT + ((size_t)g * 128 + r) * 128;
    const float* Tg = T + (size_t)g * 128 * kpad;
    float s = 0.f;
    for (int i = 0; i < n; ++i) s += Sr[i] * Tg[i * kpad + cc];
    float val = (r == cc) ? 1.0f : s;
    A_out[((size_t)g * k + r) * k + cc] = val;
    AT_out[((size_t)g * k + cc) * k + r] = val;
    if (val != 0.0f)
        atomicOr(&Mb_out[((size_t)g * 128 + cc) * 4 + (r >> 5)], 1u << (r & 31));
}

// ------------------------------------------------------------- classifier ---
__global__ __launch_bounds__(256) void k_final(
    const float* __restrict__ xs,     // [5][16][128]
    const float* __restrict__ w1, const float* __restrict__ b1,
    const float* __restrict__ w2, const float* __restrict__ b2,
    float* __restrict__ out)
{
    const int g = blockIdx.x;
    __shared__ float j_s[640];
    __shared__ float z1[128];
    const int tid = threadIdx.x, lane = tid & 63, wid = tid >> 6;  // 4 waves

    for (int idx = tid; idx < 640; idx += 256) {
        int t = idx >> 7, c = idx & 127;
        j_s[idx] = xs[t * 2048 + g * 128 + c];
    }
    __syncthreads();
    for (int c2 = wid; c2 < 128; c2 += 4) {
        const float* wrow = w1 + (size_t)c2 * 640;
        float s = 0.f;
        #pragma unroll
        for (int it = 0; it < 10; ++it) {
            int kk = it * 64 + lane;
            s += j_s[kk] * wrow[kk];
        }
        for (int off = 32; off; off >>= 1) s += __shfl_xor(s, off);
        if (lane == 0) z1[c2] = fmaxf(s + b1[c2], 0.0f);
    }
    __syncthreads();
    if (wid == 0) {
        float zv0 = z1[lane], zv1 = z1[lane + 64];
        float za = zv0 * w2[lane] + zv1 * w2[lane + 64];
        float zb = zv0 * w2[128 + lane] + zv1 * w2[192 + lane];
        for (int off = 32; off; off >>= 1) {
            za += __shfl_xor(za, off);
            zb += __shfl_xor(zb, off);
        }
        if (lane == 0) {
            za += b2[0]; zb += b2[1];
            float m = fmaxf(za, zb);
            float lse = m + logf(expf(za - m) + expf(zb - m));
            out[g * 2 + 0] = za - lse;
            out[g * 2 + 1] = zb - lse;
        }
    }
}

// ---------------------------------------------------------------------------
extern "C" void kernel_launch(void* const* d_in, const int* in_sizes, int n_in,
                              void* d_out, int out_size, void* d_ws, size_t ws_size,
                              hipStream_t stream)
{
    (void)n_in; (void)out_size; (void)ws_size;
    const float* x        = (const float*)d_in[0];
    const int*   ei       = (const int*)  d_in[1];
    const float* c0_wrel  = (const float*)d_in[2];
    const float* c0_brel  = (const float*)d_in[3];
    const float* c0_wroot = (const float*)d_in[4];
    const float* cw_rel   = (const float*)d_in[5];
    const float* cb_rel   = (const float*)d_in[6];
    const float* cw_root  = (const float*)d_in[7];
    const float* p_lin_w  = (const float*)d_in[8];
    const float* p_lin_b  = (const float*)d_in[9];
    const float* p_att_w  = (const float*)d_in[10];
    const float* p_att_b  = (const float*)d_in[11];
    const float* p_le1_w  = (const float*)d_in[12];
    const float* p_le1_b  = (const float*)d_in[13];
    const float* p_le2_w  = (const float*)d_in[14];
    const float* p_le3_w  = (const float*)d_in[15];
    const float* p_le3_b  = (const float*)d_in[16];
    const float* lin1_w   = (const float*)d_in[17];
    const float* lin1_b   = (const float*)d_in[18];
    const float* lin2_w   = (const float*)d_in[19];
    const float* lin2_b   = (const float*)d_in[20];
    float* out = (float*)d_out;

    const int E = in_sizes[1] / 2;   // 32768

    // workspace layout (memset region first: Mb1|Rb1|xsf|Mb2|Mb3)
    u32*   Mb1 = (u32*)d_ws;                  //  8192
    u32*   Rb1 = Mb1 + 8192;                  //  8192
    float* xsf = (float*)(Rb1 + 8192);        // 10240
    u32*   Mb2 = (u32*)(xsf + 10240);         //  8192
    u32*   Mb3 = Mb2 + 8192;                  //  8192
    float* qaw = (float*)(Mb3 + 8192);        //  2048
    float* xaw = qaw + 2048;                  //  2048
    float* vbuf = xaw + 2048;                 //  256 (2 x 128)
    float* c0buf = vbuf + 256;                //  2 (+pad 2)
    float* agg = c0buf + 4;                   // 262144 (pool T scratch)
    float* hA  = agg + 262144;                // 262144
    float* hB  = hA  + 262144;                // 262144
    float* Scm = hB  + 262144;                // 262144
    float* xnw = Scm + 262144;                // 262144
    float* Ssr = xnw + 262144;                // 16*128*112 = 229376
    float* SsT = Ssr + 229376;                // 262144
    float* A2  = SsT + 262144;                // 169744
    float* A2T = A2  + 169744;                // 169744
    float* A3  = A2T + 169744;                // 110224
    float* A3T = A3  + 110224;                // 110224
    float* Tw  = agg;                         // alias: pool T scratch

    hipMemsetAsync(d_ws, 0, (8192 + 8192 + 10240 + 8192 + 8192) * 4, stream);
    k_build<<<(E + 255) / 256, 256, 0, stream>>>(ei, Mb1, Rb1, E);
    k_prep<<<2, 128, 0, stream>>>(p_lin_w, p_lin_b, p_att_w, vbuf, c0buf);

    // conv0: Cin=64, masked (G=16 rows/block)
    k_conv<64, false><<<dim3(16, 8), 512, 0, stream>>>(
        x, Mb1, nullptr, c0_wrel, c0_brel, c0_wroot, hA, xsf + 0 * 2048, 128);
    // conv1: Cin=128, masked (G=8 rows/block)
    k_conv<128, false><<<dim3(16, 16), 512, 0, stream>>>(
        hA, Mb1, nullptr, cw_rel, cb_rel, cw_root, hB, xsf + 1 * 2048, 128);
    // pool1: n=128 -> k=103 (kpad=112)
    k_attn<<<dim3(16, 8), 512, 0, stream>>>(hB, Mb1, vbuf, c0buf, p_att_w, qaw, xaw, 128);
    k_soft<<<dim3(16, 16), 512, 0, stream>>>(Mb1, qaw, xaw, p_att_b, Scm, 128);
    k_xnew<<<dim3(16, 8), 512, 0, stream>>>(Scm, hB, xnw, 128);
    k_fit<<<16, 512, 0, stream>>>(xnw, Mb1, Scm,
                                  p_le1_w, p_le1_b, p_le2_w, p_le3_w, p_le3_b,
                                  hA, Ssr, SsT, 128, 103, 112);
    k_T_mask<<<dim3(16, 7), 512, 0, stream>>>(Rb1, Ssr, Tw, 128, 103, 112);
    k_A2<<<dim3(16, 21), 512, 0, stream>>>(SsT, Tw, A2, A2T, Mb2, 128, 103, 112);
    // conv2: dense A2
    k_conv<128, true><<<dim3(16, 13), 512, 0, stream>>>(
        hA, Mb2, A2T, cw_rel + 16384, cb_rel + 128, cw_root + 16384,
        hB, xsf + 2 * 2048, 103);
    // conv3: dense A2
    k_conv<128, true><<<dim3(16, 13), 512, 0, stream>>>(
        hB, Mb2, A2T, cw_rel + 2 * 16384, cb_rel + 2 * 128, cw_root + 2 * 16384,
        hA, xsf + 3 * 2048, 103);
    // pool2: n=103 -> k=83 (kpad=96)
    k_attn<<<dim3(16, 7), 512, 0, stream>>>(hA, Mb2, vbuf + 128, c0buf + 1,
                                            p_att_w + 256, qaw, xaw, 103);
    k_soft<<<dim3(16, 13), 512, 0, stream>>>(Mb2, qaw, xaw, p_att_b + 1, Scm, 103);
    k_xnew<<<dim3(16, 7), 512, 0, stream>>>(Scm, hA, xnw, 103);
    k_fit<<<16, 512, 0, stream>>>(xnw, Mb2, Scm,
                                  p_le1_w + 128, p_le1_b + 1, p_le2_w + 128,
                                  p_le3_w + 128, p_le3_b + 1,
                                  hB, Ssr, SsT, 103, 83, 96);
    k_T_dense<<<dim3(16, 5), 512, 0, stream>>>(A2, Ssr, Tw, 103, 83, 96);
    k_A2<<<dim3(16, 14), 512, 0, stream>>>(SsT, Tw, A3, A3T, Mb3, 103, 83, 96);
    // conv4: dense A3
    k_conv<128, true><<<dim3(16, 11), 512, 0, stream>>>(
        hB, Mb3, A3T, cw_rel + 3 * 16384, cb_rel + 3 * 128, cw_root + 3 * 16384,
        hA, xsf + 4 * 2048, 83);

    k_final<<<16, 256, 0, stream>>>(xsf, lin1_w, lin1_b, lin2_w, lin2_b, out);
}

// Round 12
// 477.109 us; speedup vs baseline: 1.5803x; 1.0778x over previous
//
#include <hip/hip_runtime.h>

#define NEG_SLOPE 0.2f
typedef unsigned int u32;

// ------------------------------------------------------------ build bitmasks
__global__ __launch_bounds__(256) void k_build(const int* __restrict__ ei,
                                               u32* __restrict__ Mb,
                                               u32* __restrict__ Rb, int E)
{
    int e = blockIdx.x * 256 + threadIdx.x;
    if (e >= E) return;
    int s = ei[e], d = ei[E + e];
    int g = s >> 7, ls = s & 127, ld = d & 127;
    atomicOr(&Mb[(g * 128 + ld) * 4 + (ls >> 5)], 1u << (ls & 31));  // col mask (in-edges)
    atomicOr(&Rb[(g * 128 + ls) * 4 + (ld >> 5)], 1u << (ld & 31));  // row mask (out-edges)
}

// ------------------------------------- precompute v = lin_w^T a_q, c0 = lin_b·a_q
__global__ __launch_bounds__(128) void k_prep(
    const float* __restrict__ lin_w, const float* __restrict__ lin_b,
    const float* __restrict__ att_w,
    float* __restrict__ v_out, float* __restrict__ c0_out)
{
    const int p = blockIdx.x;
    const float* lw = lin_w + p * 16384;
    const float* lb = lin_b + p * 128;
    const float* aw = att_w + p * 256;
    const int c = threadIdx.x;
    float s = 0.f;
    for (int c2 = 0; c2 < 128; ++c2) s += aw[c2] * lw[c2 * 128 + c];
    v_out[p * 128 + c] = s;
    if (c < 64) {
        float s0 = aw[c] * lb[c] + aw[c + 64] * lb[c + 64];
        for (int off = 32; off; off >>= 1) s0 += __shfl_xor(s0, off);
        if (c == 0) c0_out[p] = s0;
    }
}

// ---- fused conv: agg in registers + relu(agg@wrel^T + brel + h@wroot^T) + gpool
// group of L=CIN/2 lanes owns one row; blockIdx.z picks a 32-wide c2 slice.
// Agg recomputed per z (identical arithmetic); W-loop is 8 quads per wave.
template<int CIN, bool DENSE>
__global__ __launch_bounds__(512) void k_conv(
    const float* __restrict__ h, const u32* __restrict__ Mb,
    const float* __restrict__ AT,
    const float* __restrict__ wrel, const float* __restrict__ brel,
    const float* __restrict__ wroot,
    float* __restrict__ h_out, float* __restrict__ xs,
    int n)
{
    constexpr int L = CIN >> 1;        // lanes per row-group (32 or 64)
    constexpr int G = 512 / L;         // rows per block (16 or 8)
    constexpr int HALF = L >> 1;       // float4 slots per operand
    const int g = blockIdx.x;
    const int c2base = blockIdx.z * 32;
    const int gg = threadIdx.x / L;
    const int l  = threadIdx.x % L;
    const int jg = blockIdx.y * G + gg;
    __shared__ float tile[G * 32];

    if (jg < n) {
        const int slot = l & (HALF - 1);
        const int c4 = slot << 2;
        const float* hsrc = h + (size_t)g * n * CIN;
        const u32* mp = Mb + (g * 128 + jg) * 4;
        u32 m0 = mp[0], m1 = mp[1], m2 = mp[2], m3 = mp[3];
        float dv = fmaxf((float)(__popc(m0) + __popc(m1) + __popc(m2) + __popc(m3)), 1.0f);
        float4 acc = make_float4(0.f, 0.f, 0.f, 0.f);
        const float* hc = hsrc + c4;
        if constexpr (!DENSE) {
            // binary A: bit-iterate; lanes <HALF take words 0,1; >=HALF words 2,3
            u32 wa = (l < HALF) ? m0 : m2;
            u32 wb = (l < HALF) ? m1 : m3;
            const int ba = (l < HALF) ? 0 : 64;
            u32 u = wa;
            while (u) {
                int i = ba + __ffs(u) - 1; u &= u - 1u;
                float4 v = *(const float4*)(hc + (size_t)i * CIN);
                acc.x += v.x; acc.y += v.y; acc.z += v.z; acc.w += v.w;
            }
            u = wb;
            while (u) {
                int i = ba + 32 + __ffs(u) - 1; u &= u - 1u;
                float4 v = *(const float4*)(hc + (size_t)i * CIN);
                acc.x += v.x; acc.y += v.y; acc.z += v.z; acc.w += v.w;
            }
        } else {
            // weighted A via AT row; lanes <HALF take [0,n/2), >=HALF [n/2,n)
            const float* Aj = AT + ((size_t)g * n + jg) * n;
            const int ibeg = (l < HALF) ? 0 : (n >> 1);
            const int iend = (l < HALF) ? (n >> 1) : n;
            for (int i = ibeg; i < iend; ++i) {
                float a = Aj[i];
                float4 v = *(const float4*)(hc + (size_t)i * CIN);
                acc.x += a * v.x; acc.y += a * v.y;
                acc.z += a * v.z; acc.w += a * v.w;
            }
        }
        // combine the two half-group partial sums
        acc.x += __shfl_xor(acc.x, HALF, L);
        acc.y += __shfl_xor(acc.y, HALF, L);
        acc.z += __shfl_xor(acc.z, HALF, L);
        acc.w += __shfl_xor(acc.w, HALF, L);

        float4 xv;
        if (l < HALF) {
            xv.x = acc.x / dv; xv.y = acc.y / dv;
            xv.z = acc.z / dv; xv.w = acc.w / dv;
        } else {
            xv = *(const float4*)(hsrc + (size_t)jg * CIN + c4);
        }

        const float* wbase = (l < HALF) ? (wrel + (l << 2))
                                        : (wroot + ((l - HALF) << 2));
        for (int c2o = 0; c2o < 32; c2o += 4) {
            const int c2 = c2base + c2o;
            float4 w0 = *(const float4*)(wbase + (size_t)(c2 + 0) * CIN);
            float4 w1 = *(const float4*)(wbase + (size_t)(c2 + 1) * CIN);
            float4 w2 = *(const float4*)(wbase + (size_t)(c2 + 2) * CIN);
            float4 w3 = *(const float4*)(wbase + (size_t)(c2 + 3) * CIN);
            float a0 = xv.x * w0.x + xv.y * w0.y + xv.z * w0.z + xv.w * w0.w;
            float a1 = xv.x * w1.x + xv.y * w1.y + xv.z * w1.z + xv.w * w1.w;
            float a2 = xv.x * w2.x + xv.y * w2.y + xv.z * w2.z + xv.w * w2.w;
            float a3 = xv.x * w3.x + xv.y * w3.y + xv.z * w3.z + xv.w * w3.w;
            #pragma unroll
            for (int off = L >> 1; off; off >>= 1) {
                a0 += __shfl_xor(a0, off, L);
                a1 += __shfl_xor(a1, off, L);
                a2 += __shfl_xor(a2, off, L);
                a3 += __shfl_xor(a3, off, L);
            }
            if (l == 0) {
                tile[gg * 32 + c2o + 0] = fmaxf(a0 + brel[c2 + 0], 0.0f);
                tile[gg * 32 + c2o + 1] = fmaxf(a1 + brel[c2 + 1], 0.0f);
                tile[gg * 32 + c2o + 2] = fmaxf(a2 + brel[c2 + 2], 0.0f);
                tile[gg * 32 + c2o + 3] = fmaxf(a3 + brel[c2 + 3], 0.0f);
            }
        }
    } else {
        for (int c2o = l; c2o < 32; c2o += L) tile[gg * 32 + c2o] = 0.0f;
    }
    __syncthreads();

    const int tid = threadIdx.x;
    // coalesced h_out writes (this block's 32-col slice)
    for (int idx = tid; idx < G * 8; idx += 512) {
        int r = idx >> 3, c4 = (idx & 7) << 2;
        int j2 = blockIdx.y * G + r;
        if (j2 < n)
            *(float4*)(h_out + ((size_t)g * n + j2) * 128 + c2base + c4) =
                *(const float4*)(tile + r * 32 + c4);
    }
    // gpool partials: one atomic per column per (g, y) block
    if (tid < 32) {
        float s = 0.f;
        #pragma unroll
        for (int r = 0; r < G; ++r) s += tile[r * 32 + tid];
        atomicAdd(&xs[g * 128 + c2base + tid], s / (float)n);
    }
}

// ------------- pool stage 1a: qa[j] = maskedColMax(h)·v + c0 ; xa[i] = h[i]·a_x
__global__ __launch_bounds__(512) void k_attn(
    const float* __restrict__ h, const u32* __restrict__ Mb_g,
    const float* __restrict__ v_g, const float* __restrict__ c0_g,
    const float* __restrict__ att_w,
    float* __restrict__ qa_g, float* __restrict__ xa_g, int n)
{
    const int g = blockIdx.x;
    const int tid = threadIdx.x;
    const int hw = tid >> 5, ln = tid & 31;
    const float* hg = h + (size_t)g * n * 128;
    const int j = blockIdx.y * 16 + hw;
    if (j < n) {
        u32 m[4];
        m[0] = Mb_g[(g * 128 + j) * 4 + 0]; m[1] = Mb_g[(g * 128 + j) * 4 + 1];
        m[2] = Mb_g[(g * 128 + j) * 4 + 2]; m[3] = Mb_g[(g * 128 + j) * 4 + 3];
        m[j >> 5] |= 1u << (j & 31);                  // diagonal
        float4 mx = make_float4(-1e30f, -1e30f, -1e30f, -1e30f);
        #pragma unroll
        for (int ww = 0; ww < 4; ++ww) {
            u32 u = m[ww];
            while (u) {
                int i = (ww << 5) + __ffs(u) - 1; u &= u - 1u;
                float4 hv = *(const float4*)(hg + (size_t)i * 128 + ln * 4);
                mx.x = fmaxf(mx.x, hv.x); mx.y = fmaxf(mx.y, hv.y);
                mx.z = fmaxf(mx.z, hv.z); mx.w = fmaxf(mx.w, hv.w);
            }
        }
        float4 vv = *(const float4*)(v_g + ln * 4);
        float acc = mx.x * vv.x + mx.y * vv.y + mx.z * vv.z + mx.w * vv.w;
        #pragma unroll
        for (int off = 16; off; off >>= 1) acc += __shfl_xor(acc, off, 32);
        if (ln == 0) qa_g[g * 128 + j] = acc + c0_g[0];
    }
    const int i = blockIdx.y * 16 + hw;
    if (i < n) {
        float4 hv = *(const float4*)(hg + (size_t)i * 128 + ln * 4);
        float4 aw = *(const float4*)(att_w + 128 + ln * 4);
        float s = hv.x * aw.x + hv.y * aw.y + hv.z * aw.z + hv.w * aw.w;
        #pragma unroll
        for (int off = 16; off; off >>= 1) s += __shfl_xor(s, off, 32);
        if (ln == 0) xa_g[g * 128 + i] = s;
    }
}

// ------------- pool stage 1b: masked column softmax -> S_cm (wave per column)
__global__ __launch_bounds__(512) void k_soft(
    const u32* __restrict__ Mb_g, const float* __restrict__ qa_g,
    const float* __restrict__ xa_g, const float* __restrict__ att_bp,
    float* __restrict__ S_cm, int n)
{
    const int g = blockIdx.x;
    const int tid = threadIdx.x, lane = tid & 63, wid = tid >> 6;
    const int j = blockIdx.y * 8 + wid;
    if (j >= n) return;
    const float att_b = att_bp[0];
    u32 m[4];
    m[0] = Mb_g[(g * 128 + j) * 4 + 0]; m[1] = Mb_g[(g * 128 + j) * 4 + 1];
    m[2] = Mb_g[(g * 128 + j) * 4 + 2]; m[3] = Mb_g[(g * 128 + j) * 4 + 3];
    m[j >> 5] |= 1u << (j & 31);                      // diagonal
    const float qaj = qa_g[g * 128 + j];
    const int i0 = lane, i1 = lane + 64;
    const bool b0 = (i0 < n) && ((m[i0 >> 5] >> (i0 & 31)) & 1u);
    const bool b1 = (i1 < n) && ((m[i1 >> 5] >> (i1 & 31)) & 1u);
    float l0 = -1e30f, l1 = -1e30f;
    if (b0) { float t = xa_g[g * 128 + i0] + qaj + att_b; l0 = (t >= 0.f) ? t : NEG_SLOPE * t; }
    if (b1) { float t = xa_g[g * 128 + i1] + qaj + att_b; l1 = (t >= 0.f) ? t : NEG_SLOPE * t; }
    float mm = fmaxf(l0, l1);
    for (int off = 32; off; off >>= 1) mm = fmaxf(mm, __shfl_xor(mm, off));
    float e0 = b0 ? expf(l0 - mm) : 0.f;
    float e1 = b1 ? expf(l1 - mm) : 0.f;
    float s = e0 + e1;
    for (int off = 32; off; off >>= 1) s += __shfl_xor(s, off);
    float* Sj = S_cm + ((size_t)g * 128 + j) * 128;
    if (i0 < n) Sj[i0] = e0 / s;
    if (i1 < n) Sj[i1] = e1 / s;
}

// ---------------------------------------- pool stage 2: x_new = S_cm @ h
__global__ __launch_bounds__(512) void k_xnew(
    const float* __restrict__ S_cm, const float* __restrict__ h,
    float* __restrict__ xn, int n)
{
    const int g = blockIdx.x;
    int idx = blockIdx.y * 512 + threadIdx.x;
    if (idx >= n * 32) return;
    int j = idx >> 5, c4 = (idx & 31) << 2;
    const float* Sj = S_cm + ((size_t)g * 128 + j) * 128;
    const float* hg = h + (size_t)g * n * 128 + c4;
    float sx = 0.f, sy = 0.f, sz = 0.f, sw = 0.f;
    for (int i = 0; i < n; ++i) {
        float sv = Sj[i];
        float4 hv = *(const float4*)(hg + (size_t)i * 128);
        sx += sv * hv.x; sy += sv * hv.y; sz += sv * hv.z; sw += sv * hv.w;
    }
    float4 o; o.x = sx; o.y = sy; o.z = sz; o.w = sw;
    *(float4*)(xn + ((size_t)g * 128 + j) * 128 + c4) = o;
}

// ------------- pool stage 3: fitness, top-k, h_out, Sselr gathers
__global__ __launch_bounds__(512) void k_fit(
    const float* __restrict__ xn, const u32* __restrict__ Mb_g,
    const float* __restrict__ S_cm,
    const float* __restrict__ le1_w, const float* __restrict__ le1_bp,
    const float* __restrict__ le2_w, const float* __restrict__ le3_w,
    const float* __restrict__ le3_bp,
    float* __restrict__ h_out, float* __restrict__ Sselr, float* __restrict__ SselrT,
    int n, int k, int kpad)
{
    const int g = blockIdx.x;
    const float* xg = xn + (size_t)g * 128 * 128;
    __shared__ float a_s[128], b_s[128], c3_s[128], fit_s[128];
    __shared__ int perm_s[128];
    const int tid = threadIdx.x, lane = tid & 63, wid = tid >> 6;

    for (int j = wid; j < n; j += 8) {
        float x0 = xg[j * 128 + lane], x1 = xg[j * 128 + 64 + lane];
        float s1 = x0 * le1_w[lane] + x1 * le1_w[64 + lane];
        float s2 = x0 * le2_w[lane] + x1 * le2_w[64 + lane];
        float s3 = x0 * le3_w[lane] + x1 * le3_w[64 + lane];
        for (int off = 32; off; off >>= 1) {
            s1 += __shfl_xor(s1, off);
            s2 += __shfl_xor(s2, off);
            s3 += __shfl_xor(s3, off);
        }
        if (lane == 0) { a_s[j] = s1 + le1_bp[0]; b_s[j] = s2; c3_s[j] = s3; }
    }
    __syncthreads();
    for (int j = tid; j < n; j += 512) {
        u32 m[4];
        m[0] = Mb_g[(g * 128 + j) * 4 + 0]; m[1] = Mb_g[(g * 128 + j) * 4 + 1];
        m[2] = Mb_g[(g * 128 + j) * 4 + 2]; m[3] = Mb_g[(g * 128 + j) * 4 + 3];
        m[j >> 5] |= 1u << (j & 31);                  // diagonal
        float dv = (float)(__popc(m[0]) + __popc(m[1]) + __popc(m[2]) + __popc(m[3]));
        float s = 0.f;
        #pragma unroll
        for (int ww = 0; ww < 4; ++ww) {
            u32 u = m[ww];
            while (u) { int i = (ww << 5) + __ffs(u) - 1; u &= u - 1u; s += a_s[i]; }
        }
        float f = s - dv * b_s[j] + c3_s[j] + le3_bp[0];
        fit_s[j] = 1.0f / (1.0f + expf(-f));
    }
    __syncthreads();
    // top-k by rank (ties -> lower index, matches lax.top_k)
    for (int j = tid; j < n; j += 512) {
        float fj = fit_s[j];
        int r = 0;
        for (int j2 = 0; j2 < n; ++j2) {
            float f2 = fit_s[j2];
            if (f2 > fj || (f2 == fj && j2 < j)) ++r;
        }
        if (r < k) perm_s[r] = j;
    }
    __syncthreads();
    // h_out[r] = x_new[perm[r]] * fit[perm[r]]
    for (int idx = tid; idx < k * 32; idx += 512) {
        int r = idx >> 5, c4 = (idx & 31) << 2;
        int p = perm_s[r]; float f = fit_s[p];
        float4 v = *(const float4*)(xg + p * 128 + c4);
        v.x *= f; v.y *= f; v.z *= f; v.w *= f;
        *(float4*)(h_out + ((size_t)g * k + r) * 128 + c4) = v;
    }
    // SselrT[r][i] = S_cm[perm[r]][i]   (row gather, coalesced)
    for (int idx = tid; idx < k * 32; idx += 512) {
        int r = idx >> 5, c4 = (idx & 31) << 2;
        float4 v = *(const float4*)(S_cm + ((size_t)g * 128 + perm_s[r]) * 128 + c4);
        *(float4*)(SselrT + ((size_t)g * 128 + r) * 128 + c4) = v;
    }
    // Sselr[i][cc] = S_cm[perm[cc]][i]  (coalesced reads, scattered 4B writes)
    for (int idx = tid; idx < k * n; idx += 512) {
        int cc = idx / n, i = idx - cc * n;
        Sselr[((size_t)g * 128 + i) * kpad + cc] =
            S_cm[((size_t)g * 128 + perm_s[cc]) * 128 + i];
    }
}

// ---------------------------------------- pool stage 4: T = A_d @ S_sel
__global__ __launch_bounds__(512) void k_T_mask(
    const u32* __restrict__ Rb, const float* __restrict__ Sselr,
    float* __restrict__ T, int n, int k, int kpad)
{
    const int g = blockIdx.x;
    const int ccq = (k + 3) >> 2;
    int idx = blockIdx.y * 512 + threadIdx.x;
    if (idx >= n * ccq) return;
    int i = idx / ccq, c4 = (idx - i * ccq) << 2;
    u32 m[4];
    m[0] = Rb[(g * 128 + i) * 4 + 0]; m[1] = Rb[(g * 128 + i) * 4 + 1];
    m[2] = Rb[(g * 128 + i) * 4 + 2]; m[3] = Rb[(g * 128 + i) * 4 + 3];
    m[i >> 5] |= 1u << (i & 31);                      // diagonal
    float sx = 0.f, sy = 0.f, sz = 0.f, sw = 0.f;
    #pragma unroll
    for (int ww = 0; ww < 4; ++ww) {
        u32 u = m[ww];
        while (u) {
            int j = (ww << 5) + __ffs(u) - 1; u &= u - 1u;
            float4 v = *(const float4*)(Sselr + ((size_t)g * 128 + j) * kpad + c4);
            sx += v.x; sy += v.y; sz += v.z; sw += v.w;
        }
    }
    float4 o; o.x = sx; o.y = sy; o.z = sz; o.w = sw;
    *(float4*)(T + ((size_t)g * 128 + i) * kpad + c4) = o;
}

__global__ __launch_bounds__(512) void k_T_dense(
    const float* __restrict__ A, const float* __restrict__ Sselr,
    float* __restrict__ T, int n, int k, int kpad)
{
    const int g = blockIdx.x;
    const int ccq = (k + 3) >> 2;
    int idx = blockIdx.y * 512 + threadIdx.x;
    if (idx >= n * ccq) return;
    int i = idx / ccq, c4 = (idx - i * ccq) << 2;
    const float* Ai = A + ((size_t)g * n + i) * n;    // unit diag already present
    float sx = 0.f, sy = 0.f, sz = 0.f, sw = 0.f;
    for (int j = 0; j < n; ++j) {
        float a = Ai[j];
        float4 v = *(const float4*)(Sselr + ((size_t)g * 128 + j) * kpad + c4);
        sx += a * v.x; sy += a * v.y; sz += a * v.z; sw += a * v.w;
    }
    float4 o; o.x = sx; o.y = sy; o.z = sz; o.w = sw;
    *(float4*)(T + ((size_t)g * 128 + i) * kpad + c4) = o;
}

// ------------- pool stage 5: A2 = S_sel^T @ T (+diag, +transpose, +mask)
__global__ __launch_bounds__(512) void k_A2(
    const float* __restrict__ SselrT, const float* __restrict__ T,
    float* __restrict__ A_out, float* __restrict__ AT_out,
    u32* __restrict__ Mb_out, int n, int k, int kpad)
{
    const int g = blockIdx.x;
    int idx = blockIdx.y * 512 + threadIdx.x;
    if (idx >= k * k) return;
    int r = idx / k, cc = idx - r * k;
    const float* Sr = SselrT + ((size_t)g * 128 + r) * 128;
    const float* Tg = T + (size_t)g * 128 * kpad;
    float s = 0.f;
    for (int i = 0; i < n; ++i) s += Sr[i] * Tg[i * kpad + cc];
    float val = (r == cc) ? 1.0f : s;
    A_out[((size_t)g * k + r) * k + cc] = val;
    AT_out[((size_t)g * k + cc) * k + r] = val;
    if (val != 0.0f)
        atomicOr(&Mb_out[((size_t)g * 128 + cc) * 4 + (r >> 5)], 1u << (r & 31));
}

// ------------------------------------------------------------- classifier ---
__global__ __launch_bounds__(256) void k_final(
    const float* __restrict__ xs,     // [5][16][128]
    const float* __restrict__ w1, const float* __restrict__ b1,
    const float* __restrict__ w2, const float* __restrict__ b2,
    float* __restrict__ out)
{
    const int g = blockIdx.x;
    __shared__ float j_s[640];
    __shared__ float z1[128];
    const int tid = threadIdx.x, lane = tid & 63, wid = tid >> 6;  // 4 waves

    for (int idx = tid; idx < 640; idx += 256) {
        int t = idx >> 7, c = idx & 127;
        j_s[idx] = xs[t * 2048 + g * 128 + c];
    }
    __syncthreads();
    for (int c2 = wid; c2 < 128; c2 += 4) {
        const float* wrow = w1 + (size_t)c2 * 640;
        float s = 0.f;
        #pragma unroll
        for (int it = 0; it < 10; ++it) {
            int kk = it * 64 + lane;
            s += j_s[kk] * wrow[kk];
        }
        for (int off = 32; off; off >>= 1) s += __shfl_xor(s, off);
        if (lane == 0) z1[c2] = fmaxf(s + b1[c2], 0.0f);
    }
    __syncthreads();
    if (wid == 0) {
        float zv0 = z1[lane], zv1 = z1[lane + 64];
        float za = zv0 * w2[lane] + zv1 * w2[lane + 64];
        float zb = zv0 * w2[128 + lane] + zv1 * w2[192 + lane];
        for (int off = 32; off; off >>= 1) {
            za += __shfl_xor(za, off);
            zb += __shfl_xor(zb, off);
        }
        if (lane == 0) {
            za += b2[0]; zb += b2[1];
            float m = fmaxf(za, zb);
            float lse = m + logf(expf(za - m) + expf(zb - m));
            out[g * 2 + 0] = za - lse;
            out[g * 2 + 1] = zb - lse;
        }
    }
}

// ---------------------------------------------------------------------------
extern "C" void kernel_launch(void* const* d_in, const int* in_sizes, int n_in,
                              void* d_out, int out_size, void* d_ws, size_t ws_size,
                              hipStream_t stream)
{
    (void)n_in; (void)out_size; (void)ws_size;
    const float* x        = (const float*)d_in[0];
    const int*   ei       = (const int*)  d_in[1];
    const float* c0_wrel  = (const float*)d_in[2];
    const float* c0_brel  = (const float*)d_in[3];
    const float* c0_wroot = (const float*)d_in[4];
    const float* cw_rel   = (const float*)d_in[5];
    const float* cb_rel   = (const float*)d_in[6];
    const float* cw_root  = (const float*)d_in[7];
    const float* p_lin_w  = (const float*)d_in[8];
    const float* p_lin_b  = (const float*)d_in[9];
    const float* p_att_w  = (const float*)d_in[10];
    const float* p_att_b  = (const float*)d_in[11];
    const float* p_le1_w  = (const float*)d_in[12];
    const float* p_le1_b  = (const float*)d_in[13];
    const float* p_le2_w  = (const float*)d_in[14];
    const float* p_le3_w  = (const float*)d_in[15];
    const float* p_le3_b  = (const float*)d_in[16];
    const float* lin1_w   = (const float*)d_in[17];
    const float* lin1_b   = (const float*)d_in[18];
    const float* lin2_w   = (const float*)d_in[19];
    const float* lin2_b   = (const float*)d_in[20];
    float* out = (float*)d_out;

    const int E = in_sizes[1] / 2;   // 32768

    // workspace layout (memset region first: Mb1|Rb1|xsf|Mb2|Mb3)
    u32*   Mb1 = (u32*)d_ws;                  //  8192
    u32*   Rb1 = Mb1 + 8192;                  //  8192
    float* xsf = (float*)(Rb1 + 8192);        // 10240
    u32*   Mb2 = (u32*)(xsf + 10240);         //  8192
    u32*   Mb3 = Mb2 + 8192;                  //  8192
    float* qaw = (float*)(Mb3 + 8192);        //  2048
    float* xaw = qaw + 2048;                  //  2048
    float* vbuf = xaw + 2048;                 //  256 (2 x 128)
    float* c0buf = vbuf + 256;                //  2 (+pad 2)
    float* agg = c0buf + 4;                   // 262144 (pool T scratch)
    float* hA  = agg + 262144;                // 262144
    float* hB  = hA  + 262144;                // 262144
    float* Scm = hB  + 262144;                // 262144
    float* xnw = Scm + 262144;                // 262144
    float* Ssr = xnw + 262144;                // 16*128*112 = 229376
    float* SsT = Ssr + 229376;                // 262144
    float* A2  = SsT + 262144;                // 169744
    float* A2T = A2  + 169744;                // 169744
    float* A3  = A2T + 169744;                // 110224
    float* A3T = A3  + 110224;                // 110224
    float* Tw  = agg;                         // alias: pool T scratch

    hipMemsetAsync(d_ws, 0, (8192 + 8192 + 10240 + 8192 + 8192) * 4, stream);
    k_build<<<(E + 255) / 256, 256, 0, stream>>>(ei, Mb1, Rb1, E);
    k_prep<<<2, 128, 0, stream>>>(p_lin_w, p_lin_b, p_att_w, vbuf, c0buf);

    // conv0: Cin=64, masked (G=16 rows/block, 4-way c2 split)
    k_conv<64, false><<<dim3(16, 8, 4), 512, 0, stream>>>(
        x, Mb1, nullptr, c0_wrel, c0_brel, c0_wroot, hA, xsf + 0 * 2048, 128);
    // conv1: Cin=128, masked (G=8 rows/block, 4-way c2 split)
    k_conv<128, false><<<dim3(16, 16, 4), 512, 0, stream>>>(
        hA, Mb1, nullptr, cw_rel, cb_rel, cw_root, hB, xsf + 1 * 2048, 128);
    // pool1: n=128 -> k=103 (kpad=112)
    k_attn<<<dim3(16, 8), 512, 0, stream>>>(hB, Mb1, vbuf, c0buf, p_att_w, qaw, xaw, 128);
    k_soft<<<dim3(16, 16), 512, 0, stream>>>(Mb1, qaw, xaw, p_att_b, Scm, 128);
    k_xnew<<<dim3(16, 8), 512, 0, stream>>>(Scm, hB, xnw, 128);
    k_fit<<<16, 512, 0, stream>>>(xnw, Mb1, Scm,
                                  p_le1_w, p_le1_b, p_le2_w, p_le3_w, p_le3_b,
                                  hA, Ssr, SsT, 128, 103, 112);
    k_T_mask<<<dim3(16, 7), 512, 0, stream>>>(Rb1, Ssr, Tw, 128, 103, 112);
    k_A2<<<dim3(16, 21), 512, 0, stream>>>(SsT, Tw, A2, A2T, Mb2, 128, 103, 112);
    // conv2: dense A2
    k_conv<128, true><<<dim3(16, 13, 4), 512, 0, stream>>>(
        hA, Mb2, A2T, cw_rel + 16384, cb_rel + 128, cw_root + 16384,
        hB, xsf + 2 * 2048, 103);
    // conv3: dense A2
    k_conv<128, true><<<dim3(16, 13, 4), 512, 0, stream>>>(
        hB, Mb2, A2T, cw_rel + 2 * 16384, cb_rel + 2 * 128, cw_root + 2 * 16384,
        hA, xsf + 3 * 2048, 103);
    // pool2: n=103 -> k=83 (kpad=96)
    k_attn<<<dim3(16, 7), 512, 0, stream>>>(hA, Mb2, vbuf + 128, c0buf + 1,
                                            p_att_w + 256, qaw, xaw, 103);
    k_soft<<<dim3(16, 13), 512, 0, stream>>>(Mb2, qaw, xaw, p_att_b + 1, Scm, 103);
    k_xnew<<<dim3(16, 7), 512, 0, stream>>>(Scm, hA, xnw, 103);
    k_fit<<<16, 512, 0, stream>>>(xnw, Mb2, Scm,
                                  p_le1_w + 128, p_le1_b + 1, p_le2_w + 128,
                                  p_le3_w + 128, p_le3_b + 1,
                                  hB, Ssr, SsT, 103, 83, 96);
    k_T_dense<<<dim3(16, 5), 512, 0, stream>>>(A2, Ssr, Tw, 103, 83, 96);
    k_A2<<<dim3(16, 14), 512, 0, stream>>>(SsT, Tw, A3, A3T, Mb3, 103, 83, 96);
    // conv4: dense A3
    k_conv<128, true><<<dim3(16, 11, 4), 512, 0, stream>>>(
        hB, Mb3, A3T, cw_rel + 3 * 16384, cb_rel + 3 * 128, cw_root + 3 * 16384,
        hA, xsf + 4 * 2048, 83);

    k_final<<<16, 256, 0, stream>>>(xsf, lin1_w, lin1_b, lin2_w, lin2_b, out);
}